// Round 5
// baseline (806.234 us; speedup 1.0000x reference)
//
#include <hip/hip_runtime.h>
#include <hip/hip_bf16.h>

// ---------------- problem constants ----------------
#define BG     128        // graphs
#define NPG    512        // nodes per graph
#define NNODE  65536      // BG*NPG
#define EDGES  1048576    // BG*8192
#define NHID   128
#define DCAT   384
#define KKEEP  128        // kept nodes per (graph,cluster)
#define NPOOL  32768      // 2*BG*KKEEP
#define NGG    256        // pooled groups (2*BG)

// ---------------- workspace layout (bytes) ----------------
#define OFF_HCAT   0ull                       // 65536*384 f32 = 100663296
#define OFF_XW     100663296ull               // 65536*128 f32 (reused: xwp) ; hp at +16MB
#define OFF_DINV   134217728ull               // 65536 f32
#define OFF_DINVP  134479872ull               // 32768 f32
#define OFF_OFFA   134610944ull               // 65537 int
#define OFF_CNT    134873344ull               // 65536 int
#define OFF_ESRC   135135488ull               // 1048576 int
#define OFF_XR     139329792ull               // 65536 f32
#define OFF_XS     139591936ull               // 65536 f32
#define OFF_SCORE  139854080ull               // 65536 f32
#define OFF_POS    140116224ull               // 65536 int
#define OFF_KEEPN  140378368ull               // 32768 int
#define OFF_KEEPS  140509440ull               // 32768 f32
#define OFF_SUMS   140640512ull               // 256 int
#define OFF_XSUM   140644608ull               // 256*128 f32
#define OFF_CG     140775680ull               // 256*128 f32
#define OFF_ALPHA  140906752ull               // 32768 f32
#define OFF_PVEC   141037824ull               // 256*128 f32 (ends 141168896)
#define OFF_WT1    141170688ull               // 3*128*128 short = 98304
#define OFF_WT2    141268992ull
#define OFF_WT3    141367296ull
#define OFF_WTF    141465600ull               // 3*128*384 short = 294912

typedef __attribute__((ext_vector_type(8))) short bf16x8;
typedef __attribute__((ext_vector_type(4))) float f32x4;

__device__ inline short f2bf_s(float v) {
    __hip_bfloat16 h = __float2bfloat16(v);
    return (short)__builtin_bit_cast(unsigned short, h);
}
__device__ inline float bf2f_s(short s) {
    __hip_bfloat16 h = __builtin_bit_cast(__hip_bfloat16, (unsigned short)s);
    return __bfloat162float(h);
}

// exact truncation split: x = h + m + l + eps, |eps| <~ 2^-22|x|
__device__ inline void split3r(const f32x4 v0, const f32x4 v1,
                               bf16x8& ah, bf16x8& am, bf16x8& al) {
#pragma unroll
    for (int i = 0; i < 8; ++i) {
        float x = (i < 4) ? v0[i] : v1[i - 4];
        unsigned u = __builtin_bit_cast(unsigned, x);
        unsigned hu = u & 0xFFFF0000u;
        float r = x - __builtin_bit_cast(float, hu);
        unsigned ru = __builtin_bit_cast(unsigned, r);
        unsigned mu = ru & 0xFFFF0000u;
        float r2 = r - __builtin_bit_cast(float, mu);
        unsigned lu = __builtin_bit_cast(unsigned, r2);
        ah[i] = (short)(hu >> 16);
        am[i] = (short)(mu >> 16);
        al[i] = (short)(lu >> 16);
    }
}

// ---------------- CSR build ----------------
__global__ void k_hist(const int* __restrict__ dst, int* __restrict__ cnt, int nE) {
    int e = blockIdx.x * blockDim.x + threadIdx.x;
    if (e < nE) atomicAdd(&cnt[dst[e]], 1);
}

__global__ void k_hist_p(const int* __restrict__ src, const int* __restrict__ dst,
                         const int* __restrict__ pos, int* __restrict__ cnt, int nE) {
    int e = blockIdx.x * blockDim.x + threadIdx.x;
    if (e >= nE) return;
    int s = src[e], d = dst[e];
    if ((((s ^ d) >> 8) & 1) != 0) return;    // must be same cluster side
    int ps = pos[s], pd = pos[d];
    if (ps >= 0 && pd >= 0) atomicAdd(&cnt[pd], 1);
}

__global__ void k_scan_a(const int* __restrict__ cnt, int* __restrict__ off,
                         int* __restrict__ sums, int n) {
    __shared__ int sh[256];
    int t = threadIdx.x;
    int i = blockIdx.x * 256 + t;
    int v = (i < n) ? cnt[i] : 0;
    sh[t] = v;
    __syncthreads();
    for (int d = 1; d < 256; d <<= 1) {
        int a = (t >= d) ? sh[t - d] : 0;
        __syncthreads();
        sh[t] += a;
        __syncthreads();
    }
    if (i < n) off[i] = sh[t] - v;            // local exclusive
    if (t == 255) sums[blockIdx.x] = sh[255]; // block total
}

__global__ void k_scan_b(int* __restrict__ sums, int nb, int* __restrict__ off, int n) {
    __shared__ int sh[256];
    int t = threadIdx.x;
    int v = (t < nb) ? sums[t] : 0;
    sh[t] = v;
    __syncthreads();
    for (int d = 1; d < 256; d <<= 1) {
        int a = (t >= d) ? sh[t - d] : 0;
        __syncthreads();
        sh[t] += a;
        __syncthreads();
    }
    if (t < nb) sums[t] = sh[t] - v;          // exclusive block offsets
    if (t == 255) off[n] = sh[255];           // grand total
}

__global__ void k_scan_c(int* __restrict__ off, const int* __restrict__ sums, int n) {
    int i = blockIdx.x * blockDim.x + threadIdx.x;
    if (i < n) off[i] += sums[i >> 8];
}

__global__ void k_fill(const int* __restrict__ src, const int* __restrict__ dst,
                       const int* __restrict__ off, int* __restrict__ cur,
                       int* __restrict__ esrc, int nE) {
    int e = blockIdx.x * blockDim.x + threadIdx.x;
    if (e >= nE) return;
    int d = dst[e];
    int p = off[d] + atomicAdd(&cur[d], 1);
    esrc[p] = src[e];
}

__global__ void k_fill_p(const int* __restrict__ src, const int* __restrict__ dst,
                         const int* __restrict__ pos, const int* __restrict__ off,
                         int* __restrict__ cur, int* __restrict__ esrc, int nE) {
    int e = blockIdx.x * blockDim.x + threadIdx.x;
    if (e >= nE) return;
    int s = src[e], d = dst[e];
    if ((((s ^ d) >> 8) & 1) != 0) return;
    int ps = pos[s], pd = pos[d];
    if (ps < 0 || pd < 0) return;
    int p = off[pd] + atomicAdd(&cur[pd], 1);
    esrc[p] = ps;
}

__global__ void k_dinv(const int* __restrict__ off, float* __restrict__ dinv, int n) {
    int v = blockIdx.x * blockDim.x + threadIdx.x;
    if (v >= n) return;
    float deg = 1.0f + (float)(off[v + 1] - off[v]);
    dinv[v] = 1.0f / sqrtf(deg);
}

// ---------------- W split prep (all 4 weights, one launch) ----------------
// W[K][128] f32 -> 3 bf16 planes, transposed [128][K]
__device__ inline void wsplit_one(const float* W, short* Wt, int Kd, int i) {
    int tot = 128 * Kd;
    int n = i / Kd, k = i % Kd;
    float v = W[(size_t)k * 128 + n];
    short h = f2bf_s(v);
    float r = v - bf2f_s(h);
    short m = f2bf_s(r);
    float r2 = r - bf2f_s(m);
    short l = f2bf_s(r2);
    Wt[i] = h;
    Wt[tot + i] = m;
    Wt[2 * tot + i] = l;
}

__global__ void k_wsplit_all(const float* __restrict__ W1, const float* __restrict__ W2,
                             const float* __restrict__ W3, const float* __restrict__ Wf,
                             short* __restrict__ wt1, short* __restrict__ wt2,
                             short* __restrict__ wt3, short* __restrict__ wtf) {
    int i = blockIdx.x * 256 + threadIdx.x;
    if (i < 16384)      wsplit_one(W1, wt1, 128, i);
    else if (i < 32768) wsplit_one(W2, wt2, 128, i - 16384);
    else if (i < 49152) wsplit_one(W3, wt3, 128, i - 32768);
    else if (i < 98304) wsplit_one(Wf, wtf, 384, i - 49152);
}

// ---------------- LDS-free MFMA split-3 GEMM: C[M][128] = A[M][Kd] @ W[Kd][128] ----
// 256 thr = 4 waves; block = 64 rows; wave w owns rows [m0+16w, m0+16w+16).
// A loaded f32 direct from global, split in registers. Wt = 3 bf16 planes [128][Kd].
// GATHER: A row = rowmap[m]; rowscale applied to C rows (scale commutes with @W).
template <bool GATHER>
__global__ void __launch_bounds__(256)
k_gemm3(const float* __restrict__ A, int lda, int Kd,
        const int* __restrict__ rowmap, const float* __restrict__ rowscale,
        const short* __restrict__ Wt, float* __restrict__ C) {
    int t = threadIdx.x;
    int w = t >> 6, l = t & 63;
    int m0 = blockIdx.x * 64;
    int mrow = m0 + (w << 4) + (l & 15);
    int arow = GATHER ? rowmap[mrow] : mrow;
    int kg = (l >> 4) << 3;                 // 0,8,16,24
    const int ps = 128 * Kd;                // Wt plane stride
    const size_t abase = (size_t)arow * lda + kg;
    f32x4 acc[8];
#pragma unroll
    for (int j = 0; j < 8; ++j) acc[j] = (f32x4){0.f, 0.f, 0.f, 0.f};

    for (int ks = 0; ks < Kd; ks += 32) {
        f32x4 v0 = *reinterpret_cast<const f32x4*>(&A[abase + ks]);
        f32x4 v1 = *reinterpret_cast<const f32x4*>(&A[abase + ks + 4]);
        bf16x8 aH, aM, aL;
        split3r(v0, v1, aH, aM, aL);
#pragma unroll
        for (int j = 0; j < 8; ++j) {
            const short* bp = &Wt[(size_t)(j * 16 + (l & 15)) * Kd + ks + kg];
            bf16x8 bH = *reinterpret_cast<const bf16x8*>(bp);
            bf16x8 bM = *reinterpret_cast<const bf16x8*>(bp + ps);
            bf16x8 bL = *reinterpret_cast<const bf16x8*>(bp + 2 * ps);
            acc[j] = __builtin_amdgcn_mfma_f32_16x16x32_bf16(aH, bH, acc[j], 0, 0, 0);
            acc[j] = __builtin_amdgcn_mfma_f32_16x16x32_bf16(aH, bM, acc[j], 0, 0, 0);
            acc[j] = __builtin_amdgcn_mfma_f32_16x16x32_bf16(aM, bH, acc[j], 0, 0, 0);
            acc[j] = __builtin_amdgcn_mfma_f32_16x16x32_bf16(aM, bM, acc[j], 0, 0, 0);
            acc[j] = __builtin_amdgcn_mfma_f32_16x16x32_bf16(aH, bL, acc[j], 0, 0, 0);
            acc[j] = __builtin_amdgcn_mfma_f32_16x16x32_bf16(aL, bH, acc[j], 0, 0, 0);
        }
    }
    int crow0 = m0 + (w << 4) + ((l >> 4) << 2);
    int ccol = l & 15;
    float rs0 = 1.f, rs1 = 1.f, rs2 = 1.f, rs3 = 1.f;
    if (GATHER) {
        rs0 = rowscale[crow0]; rs1 = rowscale[crow0 + 1];
        rs2 = rowscale[crow0 + 2]; rs3 = rowscale[crow0 + 3];
    }
#pragma unroll
    for (int j = 0; j < 8; ++j) {
        C[(size_t)(crow0 + 0) * 128 + j * 16 + ccol] = acc[j][0] * rs0;
        C[(size_t)(crow0 + 1) * 128 + j * 16 + ccol] = acc[j][1] * rs1;
        C[(size_t)(crow0 + 2) * 128 + j * 16 + ccol] = acc[j][2] * rs2;
        C[(size_t)(crow0 + 3) * 128 + j * 16 + ccol] = acc[j][3] * rs3;
    }
}

// ---------------- GCN aggregate via per-graph LDS staging (+fused scoring) ----
// SCORE: also accumulate xr[v] += sum_ch val*wr[ch], xs[v] += sum_ch val*ws[ch]
// (wave-reduced, one atomicAdd pair per node per channel-half).
template <int NODESG, int CHB, bool SCORE>
__global__ void __launch_bounds__(512)
k_agg_lds(const float* __restrict__ xw, const int* __restrict__ off,
          const int* __restrict__ esrc, const float* __restrict__ dinv,
          const float* __restrict__ bias, float* __restrict__ out, int ldout,
          const float* __restrict__ wr, const float* __restrict__ wss,
          float* __restrict__ xr, float* __restrict__ xs) {
    __shared__ float sx[NODESG * CHB];
    __shared__ float sdv[NODESG];
    const int NHALF = 128 / CHB;            // channel-blocks per row
    const int NSLOT = 512 / CHB;            // nodes processed in parallel
    int t    = threadIdx.x;
    int g    = blockIdx.x / NHALF;
    int half = blockIdx.x % NHALF;
    int ch0  = half * CHB;
    int gbase = g * NODESG;
    int ch   = t % CHB;
    int slot = t / CHB;

    for (int r = t; r < NODESG; r += 512) sdv[r] = dinv[gbase + r];
    __syncthreads();
    for (int r = slot; r < NODESG; r += NSLOT)
        sx[r * CHB + ch] = xw[(size_t)(gbase + r) * 128 + ch0 + ch] * sdv[r];
    __syncthreads();

    float bb = bias[ch0 + ch];
    float wrv = SCORE ? wr[ch0 + ch] : 0.f;
    float wsv = SCORE ? wss[ch0 + ch] : 0.f;
    int uslot = __builtin_amdgcn_readfirstlane(slot);
    for (int vi = uslot; vi < NODESG; vi += NSLOT) {
        int v = gbase + vi;
        int e0 = off[v], e1 = off[v + 1];
        float acc = sx[vi * CHB + ch];      // self-loop (carries dinv[v])
        int j = e0;
        for (; j + 3 < e1; j += 4) {
            float a0 = sx[(esrc[j + 0] & (NODESG - 1)) * CHB + ch];
            float a1 = sx[(esrc[j + 1] & (NODESG - 1)) * CHB + ch];
            float a2 = sx[(esrc[j + 2] & (NODESG - 1)) * CHB + ch];
            float a3 = sx[(esrc[j + 3] & (NODESG - 1)) * CHB + ch];
            acc += a0; acc += a1; acc += a2; acc += a3;
        }
        for (; j < e1; ++j)
            acc += sx[(esrc[j] & (NODESG - 1)) * CHB + ch];
        float val = fmaxf(fmaf(sdv[vi], acc, bb), 0.f);
        out[(size_t)v * ldout + ch0 + ch] = val;
        if (SCORE) {
            float pr = val * wrv, pv = val * wsv;
            for (int o = 32; o; o >>= 1) { pr += __shfl_down(pr, o); pv += __shfl_down(pv, o); }
            if ((t & 63) == 0) { atomicAdd(&xr[v], pr); atomicAdd(&xs[v], pv); }
        }
    }
}

// ---------------- score from xr/xs ----------------
__global__ void k_score(const int* __restrict__ off, const int* __restrict__ esrc,
                        const float* __restrict__ xr, const float* __restrict__ xs,
                        const float* __restrict__ pb, float* __restrict__ score) {
    int v = blockIdx.x * blockDim.x + threadIdx.x;
    if (v >= NNODE) return;
    int side = (v >> 8) & 1;
    float acc = 0.f;
    int e0 = off[v], e1 = off[v + 1];
    for (int j = e0; j < e1; ++j) {
        int s = esrc[j];
        if (((s >> 8) & 1) == side) acc += xr[s];
    }
    score[v] = tanhf(acc + xs[v] + pb[0]);
}

// ---------------- per-(graph,cluster) top-K via bitonic sort ----------------
__global__ void k_topk(const float* __restrict__ score, int* __restrict__ keepn,
                       float* __restrict__ keeps, int* __restrict__ pos) {
    __shared__ unsigned long long keys[256];
    __shared__ float sc[256];
    __shared__ int rankof[256];
    int g = blockIdx.x & 127, cl = blockIdx.x >> 7;
    int t = threadIdx.x;
    int node = g * NPG + cl * 256 + t;
    float s = score[node];
    sc[t] = s;
    rankof[t] = -1;
    unsigned u = __float_as_uint(s);
    u = (u & 0x80000000u) ? ~u : (u | 0x80000000u); // ascending order map
    unsigned dk = ~u;                               // descending
    keys[t] = ((unsigned long long)dk << 32) | (unsigned)t;
    __syncthreads();
    for (int k = 2; k <= 256; k <<= 1)
        for (int j = k >> 1; j > 0; j >>= 1) {
            int ixj = t ^ j;
            if (ixj > t) {
                bool up = ((t & k) == 0);
                unsigned long long A = keys[t], Bk = keys[ixj];
                if ((A > Bk) == up) { keys[t] = Bk; keys[ixj] = A; }
            }
            __syncthreads();
        }
    if (t < KKEEP) {
        int idx = (int)(keys[t] & 0xffffffffu);
        int pool = cl * (BG * KKEEP) + g * KKEEP + t;
        keepn[pool] = g * NPG + cl * 256 + idx;
        keeps[pool] = sc[idx];
        rankof[idx] = t;
    }
    __syncthreads();
    int r = rankof[t];
    pos[node] = (r >= 0) ? (cl * (BG * KKEEP) + g * KKEEP + r) : -1;
}

// ---------------- attention pooling ----------------
__global__ void k_xsum(const float* __restrict__ hp, float* __restrict__ xsum) {
    int gg = blockIdx.x, t = threadIdx.x; // 256 blocks x 128 threads
    float a = 0.f;
    for (int i = 0; i < KKEEP; ++i) a += hp[(size_t)(gg * KKEEP + i) * 128 + t];
    xsum[gg * 128 + t] = a * (1.0f / (float)KKEEP);
}

__global__ void k_cg(const float* __restrict__ xsum, const float* __restrict__ gpW,
                     float* __restrict__ cg) {
    __shared__ float xl[128];
    int gg = blockIdx.x, t = threadIdx.x;
    xl[t] = xsum[gg * 128 + t];
    __syncthreads();
    float a = 0.f;
    for (int k = 0; k < 128; ++k) a = fmaf(xl[k], gpW[k * 128 + t], a);
    cg[gg * 128 + t] = tanhf(a);
}

__global__ void k_alpha(const float* __restrict__ hp, const float* __restrict__ cg,
                        float* __restrict__ alpha) {
    int node = (blockIdx.x * 256 + threadIdx.x) >> 6;
    int lane = threadIdx.x & 63;
    if (node >= NPOOL) return;
    int gg = node >> 7;
    float a = 0.f;
    for (int k = lane; k < 128; k += 64)
        a = fmaf(hp[(size_t)node * 128 + k], cg[gg * 128 + k], a);
    for (int o = 32; o; o >>= 1) a += __shfl_down(a, o);
    if (lane == 0) alpha[node] = 1.f / (1.f + expf(-a));
}

__global__ void k_wsum(const float* __restrict__ hp, const float* __restrict__ alpha,
                       float* __restrict__ pvec) {
    int gg = blockIdx.x, t = threadIdx.x;
    float a = 0.f;
    for (int i = 0; i < KKEEP; ++i) {
        int node = gg * KKEEP + i;
        a = fmaf(alpha[node], hp[(size_t)node * 128 + t], a);
    }
    pvec[gg * 128 + t] = a;
}

// ---------------- MLP head + outputs (f32 out) ----------------
__global__ void k_head(const float* __restrict__ pvec,
                       const float* __restrict__ l1W, const float* __restrict__ l1b,
                       const float* __restrict__ l2W, const float* __restrict__ l2b,
                       const float* __restrict__ l3W, const float* __restrict__ l3b,
                       float* __restrict__ out) {
    __shared__ float pv[256], h1[128], h2[64];
    int g = blockIdx.x, t = threadIdx.x;
    pv[t]       = pvec[g * 128 + t];
    pv[128 + t] = pvec[(128 + g) * 128 + t];
    __syncthreads();
    float a = l1b[t];
    for (int k = 0; k < 256; ++k) a = fmaf(pv[k], l1W[k * 128 + t], a);
    h1[t] = fmaxf(a, 0.f);
    __syncthreads();
    if (t < 64) {
        float a2 = l2b[t];
        for (int k = 0; k < 128; ++k) a2 = fmaf(h1[k], l2W[k * 64 + t], a2);
        h2[t] = fmaxf(a2, 0.f);
    }
    __syncthreads();
    if (t < 10) {
        float a3 = l3b[t];
        for (int k = 0; k < 64; ++k) a3 = fmaf(h2[k], l3W[k * 10 + t], a3);
        out[65536 + g * 10 + t] = a3;
    }
}

__global__ void k_batchout(float* __restrict__ out) {
    int i = blockIdx.x * blockDim.x + threadIdx.x;
    if (i >= 65536) return;
    int v = (i < 32768) ? (i >> 8) : ((i - 32768) >> 8) + 128;
    out[i] = (float)v;
}

// ---------------- launch ----------------
extern "C" void kernel_launch(void* const* d_in, const int* in_sizes, int n_in,
                              void* d_out, int out_size, void* d_ws, size_t ws_size,
                              hipStream_t stream) {
    const float* x    = (const float*)d_in[0];
    const int*   ei   = (const int*)d_in[1];
    const int*   esrc_in = ei;
    const int*   edst_in = ei + EDGES;
    const float* W1 = (const float*)d_in[2];  const float* b1 = (const float*)d_in[3];
    const float* W2 = (const float*)d_in[4];  const float* b2 = (const float*)d_in[5];
    const float* W3 = (const float*)d_in[6];  const float* b3 = (const float*)d_in[7];
    const float* pWr = (const float*)d_in[8]; const float* pWs = (const float*)d_in[9];
    const float* pb  = (const float*)d_in[10];
    const float* fW  = (const float*)d_in[11]; const float* fb = (const float*)d_in[12];
    const float* gpW = (const float*)d_in[13];
    const float* l1W = (const float*)d_in[14]; const float* l1b = (const float*)d_in[15];
    const float* l2W = (const float*)d_in[16]; const float* l2b = (const float*)d_in[17];
    const float* l3W = (const float*)d_in[18]; const float* l3b = (const float*)d_in[19];
    float* out = (float*)d_out;

    char* ws = (char*)d_ws;
    float* hcat  = (float*)(ws + OFF_HCAT);
    float* xw    = (float*)(ws + OFF_XW);
    float* xwp   = (float*)(ws + OFF_XW);                 // reuse after conv3
    float* hp    = (float*)(ws + OFF_XW + 16777216ull);
    float* dinv  = (float*)(ws + OFF_DINV);
    float* dinvp = (float*)(ws + OFF_DINVP);
    int*   offA  = (int*)(ws + OFF_OFFA);
    int*   cnt   = (int*)(ws + OFF_CNT);
    int*   esrc  = (int*)(ws + OFF_ESRC);
    float* xr    = (float*)(ws + OFF_XR);
    float* xs    = (float*)(ws + OFF_XS);
    float* score = (float*)(ws + OFF_SCORE);
    int*   pos   = (int*)(ws + OFF_POS);
    int*   keepn = (int*)(ws + OFF_KEEPN);
    float* keeps = (float*)(ws + OFF_KEEPS);
    int*   sums  = (int*)(ws + OFF_SUMS);
    float* xsum  = (float*)(ws + OFF_XSUM);
    float* cg    = (float*)(ws + OFF_CG);
    float* alpha = (float*)(ws + OFF_ALPHA);
    float* pvec  = (float*)(ws + OFF_PVEC);
    short* wt1   = (short*)(ws + OFF_WT1);
    short* wt2   = (short*)(ws + OFF_WT2);
    short* wt3   = (short*)(ws + OFF_WT3);
    short* wtf   = (short*)(ws + OFF_WTF);

    // ---- weight split prep (one launch) ----
    k_wsplit_all<<<384, 256, 0, stream>>>(W1, W2, W3, fW, wt1, wt2, wt3, wtf);

    // ---- full-graph CSR (by dst) ----
    hipMemsetAsync(cnt, 0, NNODE * sizeof(int), stream);
    k_hist<<<EDGES / 256, 256, 0, stream>>>(edst_in, cnt, EDGES);
    k_scan_a<<<NNODE / 256, 256, 0, stream>>>(cnt, offA, sums, NNODE);
    k_scan_b<<<1, 256, 0, stream>>>(sums, NNODE / 256, offA, NNODE);
    k_scan_c<<<NNODE / 256, 256, 0, stream>>>(offA, sums, NNODE);
    hipMemsetAsync(cnt, 0, NNODE * sizeof(int), stream);
    k_fill<<<EDGES / 256, 256, 0, stream>>>(esrc_in, edst_in, offA, cnt, esrc, EDGES);
    k_dinv<<<NNODE / 256, 256, 0, stream>>>(offA, dinv, NNODE);

    // xr/xs accumulators (contiguous) zeroed once; agg layers accumulate into them
    hipMemsetAsync(xr, 0, 2 * NNODE * sizeof(float), stream);

    // ---- 3 GCN layers into hcat column slices (scoring fused into agg) ----
    k_gemm3<false><<<NNODE / 64, 256, 0, stream>>>(x, 128, 128, nullptr, nullptr, wt1, xw);
    k_agg_lds<512, 64, true><<<256, 512, 0, stream>>>(xw, offA, esrc, dinv, b1, hcat + 0, DCAT,
                                                      pWr + 0, pWs + 0, xr, xs);
    k_gemm3<false><<<NNODE / 64, 256, 0, stream>>>(hcat, DCAT, 128, nullptr, nullptr, wt2, xw);
    k_agg_lds<512, 64, true><<<256, 512, 0, stream>>>(xw, offA, esrc, dinv, b2, hcat + 128, DCAT,
                                                      pWr + 128, pWs + 128, xr, xs);
    k_gemm3<false><<<NNODE / 64, 256, 0, stream>>>(hcat + 128, DCAT, 128, nullptr, nullptr, wt3, xw);
    k_agg_lds<512, 64, true><<<256, 512, 0, stream>>>(xw, offA, esrc, dinv, b3, hcat + 256, DCAT,
                                                      pWr + 256, pWs + 256, xr, xs);

    // ---- SAGPool scoring + top-K ----
    k_score<<<NNODE / 256, 256, 0, stream>>>(offA, esrc, xr, xs, pb, score);
    k_topk<<<256, 256, 0, stream>>>(score, keepn, keeps, pos);

    // ---- pooled CSR (filtered, remapped edges) ----
    hipMemsetAsync(cnt, 0, NPOOL * sizeof(int), stream);
    k_hist_p<<<EDGES / 256, 256, 0, stream>>>(esrc_in, edst_in, pos, cnt, EDGES);
    k_scan_a<<<NPOOL / 256, 256, 0, stream>>>(cnt, offA, sums, NPOOL);
    k_scan_b<<<1, 256, 0, stream>>>(sums, NPOOL / 256, offA, NPOOL);
    k_scan_c<<<NPOOL / 256, 256, 0, stream>>>(offA, sums, NPOOL);
    hipMemsetAsync(cnt, 0, NPOOL * sizeof(int), stream);
    k_fill_p<<<EDGES / 256, 256, 0, stream>>>(esrc_in, edst_in, pos, offA, cnt, esrc, EDGES);
    k_dinv<<<NPOOL / 256, 256, 0, stream>>>(offA, dinvp, NPOOL);

    // ---- pooled GCN conv (gather rows; score-scale applied in epilogue) ----
    k_gemm3<true><<<NPOOL / 64, 256, 0, stream>>>(hcat, DCAT, DCAT, keepn, keeps, wtf, xwp);
    k_agg_lds<128, 128, false><<<256, 512, 0, stream>>>(xwp, offA, esrc, dinvp, fb, hp, 128,
                                                        nullptr, nullptr, nullptr, nullptr);

    // ---- attention pool + head ----
    k_xsum<<<NGG, 128, 0, stream>>>(hp, xsum);
    k_cg<<<NGG, 128, 0, stream>>>(xsum, gpW, cg);
    k_alpha<<<NPOOL / 4, 256, 0, stream>>>(hp, cg, alpha);
    k_wsum<<<NGG, 128, 0, stream>>>(hp, alpha, pvec);
    k_head<<<BG, 128, 0, stream>>>(pvec, l1W, l1b, l2W, l2b, l3W, l3b, out);
    k_batchout<<<256, 256, 0, stream>>>(out);
}

// Round 6
// 688.787 us; speedup vs baseline: 1.1705x; 1.1705x over previous
//
#include <hip/hip_runtime.h>
#include <hip/hip_bf16.h>

// ---------------- problem constants ----------------
#define BG     128        // graphs
#define NPG    512        // nodes per graph
#define NNODE  65536      // BG*NPG
#define EDGES  1048576    // BG*8192
#define NHID   128
#define DCAT   384
#define KKEEP  128        // kept nodes per (graph,cluster)
#define NPOOL  32768      // 2*BG*KKEEP
#define NGG    256        // pooled groups (2*BG)

// ---------------- workspace layout (bytes) ----------------
#define OFF_HCAT   0ull                       // 65536*384 f32 = 100663296
#define OFF_XW     100663296ull               // 65536*128 f32 (reused: xwp) ; hp at +16MB
#define OFF_DINV   134217728ull               // 65536 f32
#define OFF_DINVP  134479872ull               // 32768 f32
#define OFF_OFFA   134610944ull               // 65537 int
#define OFF_CNT    134873344ull               // 65536 int
#define OFF_ESRC   135135488ull               // 1048576 int
#define OFF_XR     139329792ull               // 65536 f32
#define OFF_XS     139591936ull               // 65536 f32
#define OFF_SCORE  139854080ull               // 65536 f32
#define OFF_POS    140116224ull               // 65536 int
#define OFF_KEEPN  140378368ull               // 32768 int
#define OFF_KEEPS  140509440ull               // 32768 f32
#define OFF_SUMS   140640512ull               // 256 int
#define OFF_XSUM   140644608ull               // 256*128 f32
#define OFF_CG     140775680ull               // 256*128 f32
#define OFF_ALPHA  140906752ull               // 32768 f32
#define OFF_PVEC   141037824ull               // 256*128 f32 (ends 141168896)
#define OFF_WT1    141170688ull               // 2*128*128 short = 65536 (slot 98304)
#define OFF_WT2    141268992ull
#define OFF_WT3    141367296ull
#define OFF_WTF    141465600ull               // 2*128*384 short = 196608

typedef __attribute__((ext_vector_type(8))) short bf16x8;
typedef __attribute__((ext_vector_type(4))) float f32x4;

// bf16 round-to-nearest-even, result as high-aligned 32-bit pattern
__device__ inline unsigned rtn_hi(float x) {
    unsigned u = __builtin_bit_cast(unsigned, x);
    return (u + 0x7FFFu + ((u >> 16) & 1u)) & 0xFFFF0000u;
}

// split-2 RTN: x = h + m + eps, |eps| <~ 2^-18 |x|
__device__ inline void split2(const f32x4 v0, const f32x4 v1, bf16x8& ah, bf16x8& am) {
#pragma unroll
    for (int p = 0; p < 4; ++p) {
        float x0 = (p < 2) ? v0[2 * p] : v1[2 * p - 4];
        float x1 = (p < 2) ? v0[2 * p + 1] : v1[2 * p - 3];
        unsigned h0 = rtn_hi(x0), h1 = rtn_hi(x1);
        float r0 = x0 - __builtin_bit_cast(float, h0);
        float r1 = x1 - __builtin_bit_cast(float, h1);
        unsigned m0 = rtn_hi(r0), m1 = rtn_hi(r1);
        ah[2 * p] = (short)(h0 >> 16); ah[2 * p + 1] = (short)(h1 >> 16);
        am[2 * p] = (short)(m0 >> 16); am[2 * p + 1] = (short)(m1 >> 16);
    }
}

// ---------------- CSR build ----------------
__global__ void k_hist(const int* __restrict__ dst, int* __restrict__ cnt, int nE) {
    int e = blockIdx.x * blockDim.x + threadIdx.x;
    if (e < nE) atomicAdd(&cnt[dst[e]], 1);
}

__global__ void k_hist_p(const int* __restrict__ src, const int* __restrict__ dst,
                         const int* __restrict__ pos, int* __restrict__ cnt, int nE) {
    int e = blockIdx.x * blockDim.x + threadIdx.x;
    if (e >= nE) return;
    int s = src[e], d = dst[e];
    if ((((s ^ d) >> 8) & 1) != 0) return;    // must be same cluster side
    int ps = pos[s], pd = pos[d];
    if (ps >= 0 && pd >= 0) atomicAdd(&cnt[pd], 1);
}

__global__ void k_scan_a(const int* __restrict__ cnt, int* __restrict__ off,
                         int* __restrict__ sums, int n) {
    __shared__ int sh[256];
    int t = threadIdx.x;
    int i = blockIdx.x * 256 + t;
    int v = (i < n) ? cnt[i] : 0;
    sh[t] = v;
    __syncthreads();
    for (int d = 1; d < 256; d <<= 1) {
        int a = (t >= d) ? sh[t - d] : 0;
        __syncthreads();
        sh[t] += a;
        __syncthreads();
    }
    if (i < n) off[i] = sh[t] - v;            // local exclusive
    if (t == 255) sums[blockIdx.x] = sh[255]; // block total
}

__global__ void k_scan_b(int* __restrict__ sums, int nb, int* __restrict__ off, int n) {
    __shared__ int sh[256];
    int t = threadIdx.x;
    int v = (t < nb) ? sums[t] : 0;
    sh[t] = v;
    __syncthreads();
    for (int d = 1; d < 256; d <<= 1) {
        int a = (t >= d) ? sh[t - d] : 0;
        __syncthreads();
        sh[t] += a;
        __syncthreads();
    }
    if (t < nb) sums[t] = sh[t] - v;          // exclusive block offsets
    if (t == 255) off[n] = sh[255];           // grand total
}

__global__ void k_scan_c(int* __restrict__ off, const int* __restrict__ sums, int n) {
    int i = blockIdx.x * blockDim.x + threadIdx.x;
    if (i < n) off[i] += sums[i >> 8];
}

__global__ void k_fill(const int* __restrict__ src, const int* __restrict__ dst,
                       const int* __restrict__ off, int* __restrict__ cur,
                       int* __restrict__ esrc, int nE) {
    int e = blockIdx.x * blockDim.x + threadIdx.x;
    if (e >= nE) return;
    int d = dst[e];
    int p = off[d] + atomicAdd(&cur[d], 1);
    esrc[p] = src[e];
}

__global__ void k_fill_p(const int* __restrict__ src, const int* __restrict__ dst,
                         const int* __restrict__ pos, const int* __restrict__ off,
                         int* __restrict__ cur, int* __restrict__ esrc, int nE) {
    int e = blockIdx.x * blockDim.x + threadIdx.x;
    if (e >= nE) return;
    int s = src[e], d = dst[e];
    if ((((s ^ d) >> 8) & 1) != 0) return;
    int ps = pos[s], pd = pos[d];
    if (ps < 0 || pd < 0) return;
    int p = off[pd] + atomicAdd(&cur[pd], 1);
    esrc[p] = ps;
}

__global__ void k_dinv(const int* __restrict__ off, float* __restrict__ dinv, int n) {
    int v = blockIdx.x * blockDim.x + threadIdx.x;
    if (v >= n) return;
    float deg = 1.0f + (float)(off[v + 1] - off[v]);
    dinv[v] = 1.0f / sqrtf(deg);
}

// ---------------- W split-2 prep: W[K][128] f32 -> 2 bf16 planes [128][K] ----
__device__ inline void wsplit_one(const float* W, short* Wt, int Kd, int i) {
    int tot = 128 * Kd;
    int n = i / Kd, k = i % Kd;
    float v = W[(size_t)k * 128 + n];
    unsigned h = rtn_hi(v);
    float r = v - __builtin_bit_cast(float, h);
    unsigned m = rtn_hi(r);
    Wt[i] = (short)(h >> 16);
    Wt[tot + i] = (short)(m >> 16);
}

__global__ void k_wsplit_all(const float* __restrict__ W1, const float* __restrict__ W2,
                             const float* __restrict__ W3, const float* __restrict__ Wf,
                             short* __restrict__ wt1, short* __restrict__ wt2,
                             short* __restrict__ wt3, short* __restrict__ wtf) {
    int i = blockIdx.x * 256 + threadIdx.x;
    if (i < 16384)      wsplit_one(W1, wt1, 128, i);
    else if (i < 32768) wsplit_one(W2, wt2, 128, i - 16384);
    else if (i < 49152) wsplit_one(W3, wt3, 128, i - 32768);
    else if (i < 98304) wsplit_one(Wf, wtf, 384, i - 49152);
}

// ---------------- LDS-free MFMA split-2 GEMM: C[M][128] = A[M][Kd] @ W[Kd][128] ----
// 256 thr = 4 waves; block = 64 rows; wave w owns rows [m0+16w, m0+16w+16).
// A loaded f32 direct from global, split in registers (held across j-loop).
// B loaded per (j,ks) — small transient reg footprint so loads pipeline.
template <bool GATHER>
__global__ void __launch_bounds__(256)
k_gemm2(const float* __restrict__ A, int lda, int Kd,
        const int* __restrict__ rowmap, const float* __restrict__ rowscale,
        const short* __restrict__ Wt, float* __restrict__ C) {
    int t = threadIdx.x;
    int w = t >> 6, l = t & 63;
    int m0 = blockIdx.x * 64;
    int mrow = m0 + (w << 4) + (l & 15);
    int arow = GATHER ? rowmap[mrow] : mrow;
    int kg = (l >> 4) << 3;                 // 0,8,16,24
    const int ps = 128 * Kd;                // Wt plane stride
    const float* ap = A + (size_t)arow * lda + kg;
    f32x4 acc[8];
#pragma unroll
    for (int j = 0; j < 8; ++j) acc[j] = (f32x4){0.f, 0.f, 0.f, 0.f};

    for (int kc = 0; kc < Kd; kc += 128) {
        bf16x8 aH[4], aM[4];
#pragma unroll
        for (int ks = 0; ks < 4; ++ks) {
            f32x4 v0 = *reinterpret_cast<const f32x4*>(&ap[kc + ks * 32]);
            f32x4 v1 = *reinterpret_cast<const f32x4*>(&ap[kc + ks * 32 + 4]);
            split2(v0, v1, aH[ks], aM[ks]);
        }
#pragma unroll
        for (int j = 0; j < 8; ++j) {
            const short* bp = &Wt[(size_t)(j * 16 + (l & 15)) * Kd + kc + kg];
#pragma unroll
            for (int ks = 0; ks < 4; ++ks) {
                bf16x8 bH = *reinterpret_cast<const bf16x8*>(bp + ks * 32);
                bf16x8 bM = *reinterpret_cast<const bf16x8*>(bp + ps + ks * 32);
                acc[j] = __builtin_amdgcn_mfma_f32_16x16x32_bf16(aH[ks], bH, acc[j], 0, 0, 0);
                acc[j] = __builtin_amdgcn_mfma_f32_16x16x32_bf16(aM[ks], bH, acc[j], 0, 0, 0);
                acc[j] = __builtin_amdgcn_mfma_f32_16x16x32_bf16(aH[ks], bM, acc[j], 0, 0, 0);
                acc[j] = __builtin_amdgcn_mfma_f32_16x16x32_bf16(aM[ks], bM, acc[j], 0, 0, 0);
            }
        }
    }
    int crow0 = m0 + (w << 4) + ((l >> 4) << 2);
    int ccol = l & 15;
    float rs0 = 1.f, rs1 = 1.f, rs2 = 1.f, rs3 = 1.f;
    if (GATHER) {
        rs0 = rowscale[crow0]; rs1 = rowscale[crow0 + 1];
        rs2 = rowscale[crow0 + 2]; rs3 = rowscale[crow0 + 3];
    }
#pragma unroll
    for (int j = 0; j < 8; ++j) {
        C[(size_t)(crow0 + 0) * 128 + j * 16 + ccol] = acc[j][0] * rs0;
        C[(size_t)(crow0 + 1) * 128 + j * 16 + ccol] = acc[j][1] * rs1;
        C[(size_t)(crow0 + 2) * 128 + j * 16 + ccol] = acc[j][2] * rs2;
        C[(size_t)(crow0 + 3) * 128 + j * 16 + ccol] = acc[j][3] * rs3;
    }
}

// ---------------- GCN aggregate: LDS staging + coalesced edge fetch + shfl bcast ----
// One block per (group, channel-block). Wave wv owns nodes vi = wv, wv+8, ...
// Edge srcs fetched 64-wide coalesced into a lane register, broadcast via shfl.
template <int NODESG, int CPL>   // CPL = floats per lane (1: 64-ch halves, 2: 128 ch)
__global__ void __launch_bounds__(512)
k_agg3(const float* __restrict__ xw, const int* __restrict__ off,
       const int* __restrict__ esrc, const float* __restrict__ dinv,
       const float* __restrict__ bias, float* __restrict__ out, int ldout) {
    constexpr int CHB = 64 * CPL;
    constexpr int NH = 128 / CHB;
    __shared__ float sx[NODESG * CHB];
    __shared__ float sdv[NODESG];
    int t = threadIdx.x, wv = t >> 6, lane = t & 63;
    int g = blockIdx.x / NH, half = blockIdx.x % NH;
    int ch0 = half * CHB;
    int gbase = g * NODESG;

    for (int r = t; r < NODESG; r += 512) sdv[r] = dinv[gbase + r];
    __syncthreads();
    for (int r = wv; r < NODESG; r += 8) {
        if (CPL == 1) {
            sx[r * CHB + lane] = xw[(size_t)(gbase + r) * 128 + ch0 + lane] * sdv[r];
        } else {
            float2 v = *reinterpret_cast<const float2*>(
                &xw[(size_t)(gbase + r) * 128 + ch0 + 2 * lane]);
            sx[r * CHB + 2 * lane]     = v.x * sdv[r];
            sx[r * CHB + 2 * lane + 1] = v.y * sdv[r];
        }
    }
    __syncthreads();

    float bb0 = bias[ch0 + CPL * lane];
    float bb1 = (CPL == 2) ? bias[ch0 + 2 * lane + 1] : 0.f;

    for (int vi = wv; vi < NODESG; vi += 8) {
        int v = gbase + vi;
        int e0 = off[v], e1 = off[v + 1];
        int deg = e1 - e0;
        float acc0 = sx[vi * CHB + CPL * lane];   // self-loop (carries dinv[v])
        float acc1 = (CPL == 2) ? sx[vi * CHB + 2 * lane + 1] : 0.f;
        for (int base = 0; base < deg; base += 64) {
            int cnt = min(64, deg - base);
            int sreg = (base + lane < deg) ? esrc[e0 + base + lane] : 0;
            int k = 0;
            for (; k + 4 <= cnt; k += 4) {
                int s0 = __shfl(sreg, k)     & (NODESG - 1);
                int s1 = __shfl(sreg, k + 1) & (NODESG - 1);
                int s2 = __shfl(sreg, k + 2) & (NODESG - 1);
                int s3 = __shfl(sreg, k + 3) & (NODESG - 1);
                if (CPL == 1) {
                    float a0 = sx[s0 * CHB + lane];
                    float a1 = sx[s1 * CHB + lane];
                    float a2 = sx[s2 * CHB + lane];
                    float a3 = sx[s3 * CHB + lane];
                    acc0 += a0; acc0 += a1; acc0 += a2; acc0 += a3;
                } else {
                    acc0 += sx[s0 * CHB + 2 * lane];     acc1 += sx[s0 * CHB + 2 * lane + 1];
                    acc0 += sx[s1 * CHB + 2 * lane];     acc1 += sx[s1 * CHB + 2 * lane + 1];
                    acc0 += sx[s2 * CHB + 2 * lane];     acc1 += sx[s2 * CHB + 2 * lane + 1];
                    acc0 += sx[s3 * CHB + 2 * lane];     acc1 += sx[s3 * CHB + 2 * lane + 1];
                }
            }
            for (; k < cnt; ++k) {
                int s = __shfl(sreg, k) & (NODESG - 1);
                acc0 += sx[s * CHB + CPL * lane];
                if (CPL == 2) acc1 += sx[s * CHB + 2 * lane + 1];
            }
        }
        float dv = sdv[vi];
        out[(size_t)v * ldout + ch0 + CPL * lane] = fmaxf(fmaf(dv, acc0, bb0), 0.f);
        if (CPL == 2)
            out[(size_t)v * ldout + ch0 + 2 * lane + 1] = fmaxf(fmaf(dv, acc1, bb1), 0.f);
    }
}

// ---------------- scoring ----------------
__global__ void k_xrxs(const float* __restrict__ hcat, const float* __restrict__ Wr,
                       const float* __restrict__ Ws, float* __restrict__ xr,
                       float* __restrict__ xs) {
    int wid  = (blockIdx.x * 256 + threadIdx.x) >> 6;   // node (wave per node)
    int lane = threadIdx.x & 63;
    if (wid >= NNODE) return;
    float ar = 0.f, as = 0.f;
#pragma unroll
    for (int k = lane; k < DCAT; k += 64) {
        float h = hcat[(size_t)wid * DCAT + k];
        ar = fmaf(h, Wr[k], ar);
        as = fmaf(h, Ws[k], as);
    }
    for (int o = 32; o; o >>= 1) { ar += __shfl_down(ar, o); as += __shfl_down(as, o); }
    if (lane == 0) { xr[wid] = ar; xs[wid] = as; }
}

__global__ void k_score(const int* __restrict__ off, const int* __restrict__ esrc,
                        const float* __restrict__ xr, const float* __restrict__ xs,
                        const float* __restrict__ pb, float* __restrict__ score) {
    int v = blockIdx.x * blockDim.x + threadIdx.x;
    if (v >= NNODE) return;
    int side = (v >> 8) & 1;
    float acc = 0.f;
    int e0 = off[v], e1 = off[v + 1];
    for (int j = e0; j < e1; ++j) {
        int s = esrc[j];
        if (((s >> 8) & 1) == side) acc += xr[s];
    }
    score[v] = tanhf(acc + xs[v] + pb[0]);
}

// ---------------- per-(graph,cluster) top-K via bitonic sort ----------------
__global__ void k_topk(const float* __restrict__ score, int* __restrict__ keepn,
                       float* __restrict__ keeps, int* __restrict__ pos) {
    __shared__ unsigned long long keys[256];
    __shared__ float sc[256];
    __shared__ int rankof[256];
    int g = blockIdx.x & 127, cl = blockIdx.x >> 7;
    int t = threadIdx.x;
    int node = g * NPG + cl * 256 + t;
    float s = score[node];
    sc[t] = s;
    rankof[t] = -1;
    unsigned u = __float_as_uint(s);
    u = (u & 0x80000000u) ? ~u : (u | 0x80000000u); // ascending order map
    unsigned dk = ~u;                               // descending
    keys[t] = ((unsigned long long)dk << 32) | (unsigned)t;
    __syncthreads();
    for (int k = 2; k <= 256; k <<= 1)
        for (int j = k >> 1; j > 0; j >>= 1) {
            int ixj = t ^ j;
            if (ixj > t) {
                bool up = ((t & k) == 0);
                unsigned long long A = keys[t], Bk = keys[ixj];
                if ((A > Bk) == up) { keys[t] = Bk; keys[ixj] = A; }
            }
            __syncthreads();
        }
    if (t < KKEEP) {
        int idx = (int)(keys[t] & 0xffffffffu);
        int pool = cl * (BG * KKEEP) + g * KKEEP + t;
        keepn[pool] = g * NPG + cl * 256 + idx;
        keeps[pool] = sc[idx];
        rankof[idx] = t;
    }
    __syncthreads();
    int r = rankof[t];
    pos[node] = (r >= 0) ? (cl * (BG * KKEEP) + g * KKEEP + r) : -1;
}

// ---------------- attention pooling ----------------
__global__ void k_xsum(const float* __restrict__ hp, float* __restrict__ xsum) {
    int gg = blockIdx.x, t = threadIdx.x; // 256 blocks x 128 threads
    float a = 0.f;
#pragma unroll 8
    for (int i = 0; i < KKEEP; ++i) a += hp[(size_t)(gg * KKEEP + i) * 128 + t];
    xsum[gg * 128 + t] = a * (1.0f / (float)KKEEP);
}

__global__ void k_cg(const float* __restrict__ xsum, const float* __restrict__ gpW,
                     float* __restrict__ cg) {
    __shared__ float xl[128];
    int gg = blockIdx.x, t = threadIdx.x;
    xl[t] = xsum[gg * 128 + t];
    __syncthreads();
    float a = 0.f;
#pragma unroll 4
    for (int k = 0; k < 128; ++k) a = fmaf(xl[k], gpW[k * 128 + t], a);
    cg[gg * 128 + t] = tanhf(a);
}

__global__ void k_alpha(const float* __restrict__ hp, const float* __restrict__ cg,
                        float* __restrict__ alpha) {
    int node = (blockIdx.x * 256 + threadIdx.x) >> 6;
    int lane = threadIdx.x & 63;
    if (node >= NPOOL) return;
    int gg = node >> 7;
    float a = 0.f;
    for (int k = lane; k < 128; k += 64)
        a = fmaf(hp[(size_t)node * 128 + k], cg[gg * 128 + k], a);
    for (int o = 32; o; o >>= 1) a += __shfl_down(a, o);
    if (lane == 0) alpha[node] = 1.f / (1.f + expf(-a));
}

__global__ void k_wsum(const float* __restrict__ hp, const float* __restrict__ alpha,
                       float* __restrict__ pvec) {
    int gg = blockIdx.x, t = threadIdx.x;
    float a = 0.f;
#pragma unroll 8
    for (int i = 0; i < KKEEP; ++i) {
        int node = gg * KKEEP + i;
        a = fmaf(alpha[node], hp[(size_t)node * 128 + t], a);
    }
    pvec[gg * 128 + t] = a;
}

// ---------------- MLP head + outputs (f32 out) ----------------
__global__ void k_head(const float* __restrict__ pvec,
                       const float* __restrict__ l1W, const float* __restrict__ l1b,
                       const float* __restrict__ l2W, const float* __restrict__ l2b,
                       const float* __restrict__ l3W, const float* __restrict__ l3b,
                       float* __restrict__ out) {
    __shared__ float pv[256], h1[128], h2[64];
    int g = blockIdx.x, t = threadIdx.x;
    pv[t]       = pvec[g * 128 + t];
    pv[128 + t] = pvec[(128 + g) * 128 + t];
    __syncthreads();
    float a = l1b[t];
    for (int k = 0; k < 256; ++k) a = fmaf(pv[k], l1W[k * 128 + t], a);
    h1[t] = fmaxf(a, 0.f);
    __syncthreads();
    if (t < 64) {
        float a2 = l2b[t];
        for (int k = 0; k < 128; ++k) a2 = fmaf(h1[k], l2W[k * 64 + t], a2);
        h2[t] = fmaxf(a2, 0.f);
    }
    __syncthreads();
    if (t < 10) {
        float a3 = l3b[t];
        for (int k = 0; k < 64; ++k) a3 = fmaf(h2[k], l3W[k * 10 + t], a3);
        out[65536 + g * 10 + t] = a3;
    }
}

__global__ void k_batchout(float* __restrict__ out) {
    int i = blockIdx.x * blockDim.x + threadIdx.x;
    if (i >= 65536) return;
    int v = (i < 32768) ? (i >> 8) : ((i - 32768) >> 8) + 128;
    out[i] = (float)v;
}

// ---------------- launch ----------------
extern "C" void kernel_launch(void* const* d_in, const int* in_sizes, int n_in,
                              void* d_out, int out_size, void* d_ws, size_t ws_size,
                              hipStream_t stream) {
    const float* x    = (const float*)d_in[0];
    const int*   ei   = (const int*)d_in[1];
    const int*   esrc_in = ei;
    const int*   edst_in = ei + EDGES;
    const float* W1 = (const float*)d_in[2];  const float* b1 = (const float*)d_in[3];
    const float* W2 = (const float*)d_in[4];  const float* b2 = (const float*)d_in[5];
    const float* W3 = (const float*)d_in[6];  const float* b3 = (const float*)d_in[7];
    const float* pWr = (const float*)d_in[8]; const float* pWs = (const float*)d_in[9];
    const float* pb  = (const float*)d_in[10];
    const float* fW  = (const float*)d_in[11]; const float* fb = (const float*)d_in[12];
    const float* gpW = (const float*)d_in[13];
    const float* l1W = (const float*)d_in[14]; const float* l1b = (const float*)d_in[15];
    const float* l2W = (const float*)d_in[16]; const float* l2b = (const float*)d_in[17];
    const float* l3W = (const float*)d_in[18]; const float* l3b = (const float*)d_in[19];
    float* out = (float*)d_out;

    char* ws = (char*)d_ws;
    float* hcat  = (float*)(ws + OFF_HCAT);
    float* xw    = (float*)(ws + OFF_XW);
    float* xwp   = (float*)(ws + OFF_XW);                 // reuse after conv3
    float* hp    = (float*)(ws + OFF_XW + 16777216ull);
    float* dinv  = (float*)(ws + OFF_DINV);
    float* dinvp = (float*)(ws + OFF_DINVP);
    int*   offA  = (int*)(ws + OFF_OFFA);
    int*   cnt   = (int*)(ws + OFF_CNT);
    int*   esrc  = (int*)(ws + OFF_ESRC);
    float* xr    = (float*)(ws + OFF_XR);
    float* xs    = (float*)(ws + OFF_XS);
    float* score = (float*)(ws + OFF_SCORE);
    int*   pos   = (int*)(ws + OFF_POS);
    int*   keepn = (int*)(ws + OFF_KEEPN);
    float* keeps = (float*)(ws + OFF_KEEPS);
    int*   sums  = (int*)(ws + OFF_SUMS);
    float* xsum  = (float*)(ws + OFF_XSUM);
    float* cg    = (float*)(ws + OFF_CG);
    float* alpha = (float*)(ws + OFF_ALPHA);
    float* pvec  = (float*)(ws + OFF_PVEC);
    short* wt1   = (short*)(ws + OFF_WT1);
    short* wt2   = (short*)(ws + OFF_WT2);
    short* wt3   = (short*)(ws + OFF_WT3);
    short* wtf   = (short*)(ws + OFF_WTF);

    // ---- weight split prep (one launch) ----
    k_wsplit_all<<<384, 256, 0, stream>>>(W1, W2, W3, fW, wt1, wt2, wt3, wtf);

    // ---- full-graph CSR (by dst) ----
    hipMemsetAsync(cnt, 0, NNODE * sizeof(int), stream);
    k_hist<<<EDGES / 256, 256, 0, stream>>>(edst_in, cnt, EDGES);
    k_scan_a<<<NNODE / 256, 256, 0, stream>>>(cnt, offA, sums, NNODE);
    k_scan_b<<<1, 256, 0, stream>>>(sums, NNODE / 256, offA, NNODE);
    k_scan_c<<<NNODE / 256, 256, 0, stream>>>(offA, sums, NNODE);
    hipMemsetAsync(cnt, 0, NNODE * sizeof(int), stream);
    k_fill<<<EDGES / 256, 256, 0, stream>>>(esrc_in, edst_in, offA, cnt, esrc, EDGES);
    k_dinv<<<NNODE / 256, 256, 0, stream>>>(offA, dinv, NNODE);

    // ---- 3 GCN layers into hcat column slices ----
    k_gemm2<false><<<NNODE / 64, 256, 0, stream>>>(x, 128, 128, nullptr, nullptr, wt1, xw);
    k_agg3<512, 1><<<256, 512, 0, stream>>>(xw, offA, esrc, dinv, b1, hcat + 0, DCAT);
    k_gemm2<false><<<NNODE / 64, 256, 0, stream>>>(hcat, DCAT, 128, nullptr, nullptr, wt2, xw);
    k_agg3<512, 1><<<256, 512, 0, stream>>>(xw, offA, esrc, dinv, b2, hcat + 128, DCAT);
    k_gemm2<false><<<NNODE / 64, 256, 0, stream>>>(hcat + 128, DCAT, 128, nullptr, nullptr, wt3, xw);
    k_agg3<512, 1><<<256, 512, 0, stream>>>(xw, offA, esrc, dinv, b3, hcat + 256, DCAT);

    // ---- SAGPool scoring + top-K ----
    k_xrxs<<<NNODE / 4, 256, 0, stream>>>(hcat, pWr, pWs, xr, xs);
    k_score<<<NNODE / 256, 256, 0, stream>>>(offA, esrc, xr, xs, pb, score);
    k_topk<<<256, 256, 0, stream>>>(score, keepn, keeps, pos);

    // ---- pooled CSR (filtered, remapped edges) ----
    hipMemsetAsync(cnt, 0, NPOOL * sizeof(int), stream);
    k_hist_p<<<EDGES / 256, 256, 0, stream>>>(esrc_in, edst_in, pos, cnt, EDGES);
    k_scan_a<<<NPOOL / 256, 256, 0, stream>>>(cnt, offA, sums, NPOOL);
    k_scan_b<<<1, 256, 0, stream>>>(sums, NPOOL / 256, offA, NPOOL);
    k_scan_c<<<NPOOL / 256, 256, 0, stream>>>(offA, sums, NPOOL);
    hipMemsetAsync(cnt, 0, NPOOL * sizeof(int), stream);
    k_fill_p<<<EDGES / 256, 256, 0, stream>>>(esrc_in, edst_in, pos, offA, cnt, esrc, EDGES);
    k_dinv<<<NPOOL / 256, 256, 0, stream>>>(offA, dinvp, NPOOL);

    // ---- pooled GCN conv (gather rows; score-scale applied in epilogue) ----
    k_gemm2<true><<<NPOOL / 64, 256, 0, stream>>>(hcat, DCAT, DCAT, keepn, keeps, wtf, xwp);
    k_agg3<128, 2><<<256, 512, 0, stream>>>(xwp, offA, esrc, dinvp, fb, hp, 128);

    // ---- attention pool + head ----
    k_xsum<<<NGG, 128, 0, stream>>>(hp, xsum);
    k_cg<<<NGG, 128, 0, stream>>>(xsum, gpW, cg);
    k_alpha<<<NPOOL / 4, 256, 0, stream>>>(hp, cg, alpha);
    k_wsum<<<NGG, 128, 0, stream>>>(hp, alpha, pvec);
    k_head<<<BG, 128, 0, stream>>>(pvec, l1W, l1b, l2W, l2b, l3W, l3b, out);
    k_batchout<<<256, 256, 0, stream>>>(out);
}

// Round 7
// 657.897 us; speedup vs baseline: 1.2255x; 1.0470x over previous
//
#include <hip/hip_runtime.h>
#include <hip/hip_bf16.h>

// ---------------- problem constants ----------------
#define BG     128        // graphs
#define NPG    512        // nodes per graph
#define NNODE  65536      // BG*NPG
#define EDGES  1048576    // BG*8192
#define NHID   128
#define DCAT   384
#define KKEEP  128        // kept nodes per (graph,cluster)
#define NPOOL  32768      // 2*BG*KKEEP
#define NGG    256        // pooled groups (2*BG)

// ---------------- workspace layout (bytes) ----------------
#define OFF_HCAT   0ull                       // 65536*384 f32 = 100663296
#define OFF_XW     100663296ull               // 65536*128 f32 (reused: xwp) ; hp at +16MB
#define OFF_DINV   134217728ull               // 65536 f32
#define OFF_DINVP  134479872ull               // 32768 f32
#define OFF_OFFA   134610944ull               // 65537 int
#define OFF_CNT    134873344ull               // 65536 int
#define OFF_ESRC   135135488ull               // 1048576 int
#define OFF_XR     139329792ull               // 65536 f32
#define OFF_XS     139591936ull               // 65536 f32
#define OFF_SCORE  139854080ull               // 65536 f32
#define OFF_POS    140116224ull               // 65536 int
#define OFF_KEEPN  140378368ull               // 32768 int
#define OFF_KEEPS  140509440ull               // 32768 f32
#define OFF_SUMS   140640512ull               // 256 int
#define OFF_XSUM   140644608ull               // 256*128 f32
#define OFF_CG     140775680ull               // 256*128 f32
#define OFF_ALPHA  140906752ull               // 32768 f32
#define OFF_PVEC   141037824ull               // 256*128 f32 (ends 141168896)
#define OFF_WT1    141170688ull               // 2*128*128 short = 65536 (slot 98304)
#define OFF_WT2    141268992ull
#define OFF_WT3    141367296ull
#define OFF_WTF    141465600ull               // 2*128*384 short = 196608

typedef __attribute__((ext_vector_type(8))) short bf16x8;
typedef __attribute__((ext_vector_type(4))) float f32x4;

// bf16 round-to-nearest-even, result as high-aligned 32-bit pattern
__device__ inline unsigned rtn_hi(float x) {
    unsigned u = __builtin_bit_cast(unsigned, x);
    return (u + 0x7FFFu + ((u >> 16) & 1u)) & 0xFFFF0000u;
}

// split-2 RTN: x = h + m + eps, |eps| <~ 2^-18 |x|
__device__ inline void split2(const f32x4 v0, const f32x4 v1, bf16x8& ah, bf16x8& am) {
#pragma unroll
    for (int p = 0; p < 4; ++p) {
        float x0 = (p < 2) ? v0[2 * p] : v1[2 * p - 4];
        float x1 = (p < 2) ? v0[2 * p + 1] : v1[2 * p - 3];
        unsigned h0 = rtn_hi(x0), h1 = rtn_hi(x1);
        float r0 = x0 - __builtin_bit_cast(float, h0);
        float r1 = x1 - __builtin_bit_cast(float, h1);
        unsigned m0 = rtn_hi(r0), m1 = rtn_hi(r1);
        ah[2 * p] = (short)(h0 >> 16); ah[2 * p + 1] = (short)(h1 >> 16);
        am[2 * p] = (short)(m0 >> 16); am[2 * p + 1] = (short)(m1 >> 16);
    }
}

// ---------------- CSR build ----------------
__global__ void k_hist(const int* __restrict__ dst, int* __restrict__ cnt, int nE) {
    int e = blockIdx.x * blockDim.x + threadIdx.x;
    if (e < nE) atomicAdd(&cnt[dst[e]], 1);
}

__global__ void k_hist_p(const int* __restrict__ src, const int* __restrict__ dst,
                         const int* __restrict__ pos, int* __restrict__ cnt, int nE) {
    int e = blockIdx.x * blockDim.x + threadIdx.x;
    if (e >= nE) return;
    int s = src[e], d = dst[e];
    if ((((s ^ d) >> 8) & 1) != 0) return;    // must be same cluster side
    int ps = pos[s], pd = pos[d];
    if (ps >= 0 && pd >= 0) atomicAdd(&cnt[pd], 1);
}

__global__ void k_scan_a(const int* __restrict__ cnt, int* __restrict__ off,
                         int* __restrict__ sums, int n) {
    __shared__ int sh[256];
    int t = threadIdx.x;
    int i = blockIdx.x * 256 + t;
    int v = (i < n) ? cnt[i] : 0;
    sh[t] = v;
    __syncthreads();
    for (int d = 1; d < 256; d <<= 1) {
        int a = (t >= d) ? sh[t - d] : 0;
        __syncthreads();
        sh[t] += a;
        __syncthreads();
    }
    if (i < n) off[i] = sh[t] - v;            // local exclusive
    if (t == 255) sums[blockIdx.x] = sh[255]; // block total
}

__global__ void k_scan_b(int* __restrict__ sums, int nb, int* __restrict__ off, int n) {
    __shared__ int sh[256];
    int t = threadIdx.x;
    int v = (t < nb) ? sums[t] : 0;
    sh[t] = v;
    __syncthreads();
    for (int d = 1; d < 256; d <<= 1) {
        int a = (t >= d) ? sh[t - d] : 0;
        __syncthreads();
        sh[t] += a;
        __syncthreads();
    }
    if (t < nb) sums[t] = sh[t] - v;          // exclusive block offsets
    if (t == 255) off[n] = sh[255];           // grand total
}

__global__ void k_scan_c(int* __restrict__ off, const int* __restrict__ sums, int n) {
    int i = blockIdx.x * blockDim.x + threadIdx.x;
    if (i < n) off[i] += sums[i >> 8];
}

__global__ void k_fill(const int* __restrict__ src, const int* __restrict__ dst,
                       const int* __restrict__ off, int* __restrict__ cur,
                       int* __restrict__ esrc, int nE) {
    int e = blockIdx.x * blockDim.x + threadIdx.x;
    if (e >= nE) return;
    int d = dst[e];
    int p = off[d] + atomicAdd(&cur[d], 1);
    esrc[p] = src[e];
}

__global__ void k_fill_p(const int* __restrict__ src, const int* __restrict__ dst,
                         const int* __restrict__ pos, const int* __restrict__ off,
                         int* __restrict__ cur, int* __restrict__ esrc, int nE) {
    int e = blockIdx.x * blockDim.x + threadIdx.x;
    if (e >= nE) return;
    int s = src[e], d = dst[e];
    if ((((s ^ d) >> 8) & 1) != 0) return;
    int ps = pos[s], pd = pos[d];
    if (ps < 0 || pd < 0) return;
    int p = off[pd] + atomicAdd(&cur[pd], 1);
    esrc[p] = ps;
}

__global__ void k_dinv(const int* __restrict__ off, float* __restrict__ dinv, int n) {
    int v = blockIdx.x * blockDim.x + threadIdx.x;
    if (v >= n) return;
    float deg = 1.0f + (float)(off[v + 1] - off[v]);
    dinv[v] = 1.0f / sqrtf(deg);
}

// ---------------- W split-2 prep: W[K][128] f32 -> 2 bf16 planes [128][K] ----
__device__ inline void wsplit_one(const float* W, short* Wt, int Kd, int i) {
    int tot = 128 * Kd;
    int n = i / Kd, k = i % Kd;
    float v = W[(size_t)k * 128 + n];
    unsigned h = rtn_hi(v);
    float r = v - __builtin_bit_cast(float, h);
    unsigned m = rtn_hi(r);
    Wt[i] = (short)(h >> 16);
    Wt[tot + i] = (short)(m >> 16);
}

__global__ void k_wsplit_all(const float* __restrict__ W1, const float* __restrict__ W2,
                             const float* __restrict__ W3, const float* __restrict__ Wf,
                             short* __restrict__ wt1, short* __restrict__ wt2,
                             short* __restrict__ wt3, short* __restrict__ wtf) {
    int i = blockIdx.x * 256 + threadIdx.x;
    if (i < 16384)      wsplit_one(W1, wt1, 128, i);
    else if (i < 32768) wsplit_one(W2, wt2, 128, i - 16384);
    else if (i < 49152) wsplit_one(W3, wt3, 128, i - 32768);
    else if (i < 98304) wsplit_one(Wf, wtf, 384, i - 49152);
}

// ---------------- LDS-free MFMA split-2 GEMM: C[M][128] = A[M][Kd] @ W[Kd][128] ----
// 256 thr = 4 waves; block = 64 rows; wave w owns rows [m0+16w, m0+16w+16).
// A loaded f32 direct from global, split in registers (held across j-loop).
// B loaded per (j,ks) — small transient reg footprint so loads pipeline.
template <bool GATHER>
__global__ void __launch_bounds__(256)
k_gemm2(const float* __restrict__ A, int lda, int Kd,
        const int* __restrict__ rowmap, const float* __restrict__ rowscale,
        const short* __restrict__ Wt, float* __restrict__ C) {
    int t = threadIdx.x;
    int w = t >> 6, l = t & 63;
    int m0 = blockIdx.x * 64;
    int mrow = m0 + (w << 4) + (l & 15);
    int arow = GATHER ? rowmap[mrow] : mrow;
    int kg = (l >> 4) << 3;                 // 0,8,16,24
    const int ps = 128 * Kd;                // Wt plane stride
    const float* ap = A + (size_t)arow * lda + kg;
    f32x4 acc[8];
#pragma unroll
    for (int j = 0; j < 8; ++j) acc[j] = (f32x4){0.f, 0.f, 0.f, 0.f};

    for (int kc = 0; kc < Kd; kc += 128) {
        bf16x8 aH[4], aM[4];
#pragma unroll
        for (int ks = 0; ks < 4; ++ks) {
            f32x4 v0 = *reinterpret_cast<const f32x4*>(&ap[kc + ks * 32]);
            f32x4 v1 = *reinterpret_cast<const f32x4*>(&ap[kc + ks * 32 + 4]);
            split2(v0, v1, aH[ks], aM[ks]);
        }
#pragma unroll
        for (int j = 0; j < 8; ++j) {
            const short* bp = &Wt[(size_t)(j * 16 + (l & 15)) * Kd + kc + kg];
#pragma unroll
            for (int ks = 0; ks < 4; ++ks) {
                bf16x8 bH = *reinterpret_cast<const bf16x8*>(bp + ks * 32);
                bf16x8 bM = *reinterpret_cast<const bf16x8*>(bp + ps + ks * 32);
                acc[j] = __builtin_amdgcn_mfma_f32_16x16x32_bf16(aH[ks], bH, acc[j], 0, 0, 0);
                acc[j] = __builtin_amdgcn_mfma_f32_16x16x32_bf16(aM[ks], bH, acc[j], 0, 0, 0);
                acc[j] = __builtin_amdgcn_mfma_f32_16x16x32_bf16(aH[ks], bM, acc[j], 0, 0, 0);
                acc[j] = __builtin_amdgcn_mfma_f32_16x16x32_bf16(aM[ks], bM, acc[j], 0, 0, 0);
            }
        }
    }
    int crow0 = m0 + (w << 4) + ((l >> 4) << 2);
    int ccol = l & 15;
    float rs0 = 1.f, rs1 = 1.f, rs2 = 1.f, rs3 = 1.f;
    if (GATHER) {
        rs0 = rowscale[crow0]; rs1 = rowscale[crow0 + 1];
        rs2 = rowscale[crow0 + 2]; rs3 = rowscale[crow0 + 3];
    }
#pragma unroll
    for (int j = 0; j < 8; ++j) {
        C[(size_t)(crow0 + 0) * 128 + j * 16 + ccol] = acc[j][0] * rs0;
        C[(size_t)(crow0 + 1) * 128 + j * 16 + ccol] = acc[j][1] * rs1;
        C[(size_t)(crow0 + 2) * 128 + j * 16 + ccol] = acc[j][2] * rs2;
        C[(size_t)(crow0 + 3) * 128 + j * 16 + ccol] = acc[j][3] * rs3;
    }
}

// ---------------- GCN aggregate: 16-ch blocks, 4 nodes in flight per wave ----
// Block = (group, 16-col channel block). 512 thr = 8 waves; wave splits into
// 4 sub-groups of 16 lanes, each owning one node at a time. Edge srcs loaded
// 16-wide coalesced per sub-group, broadcast via shfl(width=16). LDS stride 17
// breaks bank alignment. 36KB LDS -> 4 blocks/CU (max waves).
template <int NODESG>
__global__ void __launch_bounds__(512)
k_agg4(const float* __restrict__ xw, const int* __restrict__ off,
       const int* __restrict__ esrc, const float* __restrict__ dinv,
       const float* __restrict__ bias, float* __restrict__ out, int ldout) {
    constexpr int STR = 17;
    __shared__ float sx[NODESG * STR];
    __shared__ float sdv[NODESG];
    int t = threadIdx.x;
    int lane = t & 63;
    int wv = t >> 6;                 // 0..7
    int sub = lane >> 4;             // 0..3
    int ch = lane & 15;
    int g  = blockIdx.x >> 3;        // group
    int hb = blockIdx.x & 7;         // channel block
    int ch0 = hb * 16;
    int gbase = g * NODESG;

    for (int r = t; r < NODESG; r += 512) sdv[r] = dinv[gbase + r];
    __syncthreads();
    for (int idx = t; idx < NODESG * 16; idx += 512) {
        int r = idx >> 4, c = idx & 15;
        sx[r * STR + c] = xw[(size_t)(gbase + r) * 128 + ch0 + c] * sdv[r];
    }
    __syncthreads();

    float bb = bias[ch0 + ch];
    for (int vi = wv * 4 + sub; vi < NODESG; vi += 32) {
        int v = gbase + vi;
        int e0 = off[v], e1 = off[v + 1];
        int deg = e1 - e0;
        float acc = sx[vi * STR + ch];       // self-loop (carries dinv[v])
        for (int base = 0; base < deg; base += 16) {
            int cnt = min(16, deg - base);
            int sreg = (base + ch < deg) ? esrc[e0 + base + ch] : 0;
            int k = 0;
            for (; k + 4 <= cnt; k += 4) {
                int s0 = __shfl(sreg, k, 16)     & (NODESG - 1);
                int s1 = __shfl(sreg, k + 1, 16) & (NODESG - 1);
                int s2 = __shfl(sreg, k + 2, 16) & (NODESG - 1);
                int s3 = __shfl(sreg, k + 3, 16) & (NODESG - 1);
                float a0 = sx[s0 * STR + ch];
                float a1 = sx[s1 * STR + ch];
                float a2 = sx[s2 * STR + ch];
                float a3 = sx[s3 * STR + ch];
                acc += a0; acc += a1; acc += a2; acc += a3;
            }
            for (; k < cnt; ++k) {
                int s = __shfl(sreg, k, 16) & (NODESG - 1);
                acc += sx[s * STR + ch];
            }
        }
        out[(size_t)v * ldout + ch0 + ch] = fmaxf(fmaf(sdv[vi], acc, bb), 0.f);
    }
}

// ---------------- scoring ----------------
__global__ void k_xrxs(const float* __restrict__ hcat, const float* __restrict__ Wr,
                       const float* __restrict__ Ws, float* __restrict__ xr,
                       float* __restrict__ xs) {
    int wid  = (blockIdx.x * 256 + threadIdx.x) >> 6;   // node (wave per node)
    int lane = threadIdx.x & 63;
    if (wid >= NNODE) return;
    float ar = 0.f, as = 0.f;
#pragma unroll
    for (int k = lane; k < DCAT; k += 64) {
        float h = hcat[(size_t)wid * DCAT + k];
        ar = fmaf(h, Wr[k], ar);
        as = fmaf(h, Ws[k], as);
    }
    for (int o = 32; o; o >>= 1) { ar += __shfl_down(ar, o); as += __shfl_down(as, o); }
    if (lane == 0) { xr[wid] = ar; xs[wid] = as; }
}

__global__ void k_score(const int* __restrict__ off, const int* __restrict__ esrc,
                        const float* __restrict__ xr, const float* __restrict__ xs,
                        const float* __restrict__ pb, float* __restrict__ score) {
    int v = blockIdx.x * blockDim.x + threadIdx.x;
    if (v >= NNODE) return;
    int side = (v >> 8) & 1;
    float acc = 0.f;
    int e0 = off[v], e1 = off[v + 1];
    for (int j = e0; j < e1; ++j) {
        int s = esrc[j];
        if (((s >> 8) & 1) == side) acc += xr[s];
    }
    score[v] = tanhf(acc + xs[v] + pb[0]);
}

// ---------------- per-(graph,cluster) top-K via bitonic sort ----------------
__global__ void k_topk(const float* __restrict__ score, int* __restrict__ keepn,
                       float* __restrict__ keeps, int* __restrict__ pos) {
    __shared__ unsigned long long keys[256];
    __shared__ float sc[256];
    __shared__ int rankof[256];
    int g = blockIdx.x & 127, cl = blockIdx.x >> 7;
    int t = threadIdx.x;
    int node = g * NPG + cl * 256 + t;
    float s = score[node];
    sc[t] = s;
    rankof[t] = -1;
    unsigned u = __float_as_uint(s);
    u = (u & 0x80000000u) ? ~u : (u | 0x80000000u); // ascending order map
    unsigned dk = ~u;                               // descending
    keys[t] = ((unsigned long long)dk << 32) | (unsigned)t;
    __syncthreads();
    for (int k = 2; k <= 256; k <<= 1)
        for (int j = k >> 1; j > 0; j >>= 1) {
            int ixj = t ^ j;
            if (ixj > t) {
                bool up = ((t & k) == 0);
                unsigned long long A = keys[t], Bk = keys[ixj];
                if ((A > Bk) == up) { keys[t] = Bk; keys[ixj] = A; }
            }
            __syncthreads();
        }
    if (t < KKEEP) {
        int idx = (int)(keys[t] & 0xffffffffu);
        int pool = cl * (BG * KKEEP) + g * KKEEP + t;
        keepn[pool] = g * NPG + cl * 256 + idx;
        keeps[pool] = sc[idx];
        rankof[idx] = t;
    }
    __syncthreads();
    int r = rankof[t];
    pos[node] = (r >= 0) ? (cl * (BG * KKEEP) + g * KKEEP + r) : -1;
}

// ---------------- attention pooling ----------------
__global__ void k_xsum(const float* __restrict__ hp, float* __restrict__ xsum) {
    int gg = blockIdx.x, t = threadIdx.x; // 256 blocks x 128 threads
    float a = 0.f;
#pragma unroll 8
    for (int i = 0; i < KKEEP; ++i) a += hp[(size_t)(gg * KKEEP + i) * 128 + t];
    xsum[gg * 128 + t] = a * (1.0f / (float)KKEEP);
}

__global__ void k_cg(const float* __restrict__ xsum, const float* __restrict__ gpW,
                     float* __restrict__ cg) {
    __shared__ float xl[128];
    int gg = blockIdx.x, t = threadIdx.x;
    xl[t] = xsum[gg * 128 + t];
    __syncthreads();
    float a = 0.f;
#pragma unroll 4
    for (int k = 0; k < 128; ++k) a = fmaf(xl[k], gpW[k * 128 + t], a);
    cg[gg * 128 + t] = tanhf(a);
}

__global__ void k_alpha(const float* __restrict__ hp, const float* __restrict__ cg,
                        float* __restrict__ alpha) {
    int node = (blockIdx.x * 256 + threadIdx.x) >> 6;
    int lane = threadIdx.x & 63;
    if (node >= NPOOL) return;
    int gg = node >> 7;
    float a = 0.f;
    for (int k = lane; k < 128; k += 64)
        a = fmaf(hp[(size_t)node * 128 + k], cg[gg * 128 + k], a);
    for (int o = 32; o; o >>= 1) a += __shfl_down(a, o);
    if (lane == 0) alpha[node] = 1.f / (1.f + expf(-a));
}

__global__ void k_wsum(const float* __restrict__ hp, const float* __restrict__ alpha,
                       float* __restrict__ pvec) {
    int gg = blockIdx.x, t = threadIdx.x;
    float a = 0.f;
#pragma unroll 8
    for (int i = 0; i < KKEEP; ++i) {
        int node = gg * KKEEP + i;
        a = fmaf(alpha[node], hp[(size_t)node * 128 + t], a);
    }
    pvec[gg * 128 + t] = a;
}

// ---------------- MLP head + outputs (f32 out) ----------------
__global__ void k_head(const float* __restrict__ pvec,
                       const float* __restrict__ l1W, const float* __restrict__ l1b,
                       const float* __restrict__ l2W, const float* __restrict__ l2b,
                       const float* __restrict__ l3W, const float* __restrict__ l3b,
                       float* __restrict__ out) {
    __shared__ float pv[256], h1[128], h2[64];
    int g = blockIdx.x, t = threadIdx.x;
    pv[t]       = pvec[g * 128 + t];
    pv[128 + t] = pvec[(128 + g) * 128 + t];
    __syncthreads();
    float a = l1b[t];
    for (int k = 0; k < 256; ++k) a = fmaf(pv[k], l1W[k * 128 + t], a);
    h1[t] = fmaxf(a, 0.f);
    __syncthreads();
    if (t < 64) {
        float a2 = l2b[t];
        for (int k = 0; k < 128; ++k) a2 = fmaf(h1[k], l2W[k * 64 + t], a2);
        h2[t] = fmaxf(a2, 0.f);
    }
    __syncthreads();
    if (t < 10) {
        float a3 = l3b[t];
        for (int k = 0; k < 64; ++k) a3 = fmaf(h2[k], l3W[k * 10 + t], a3);
        out[65536 + g * 10 + t] = a3;
    }
}

__global__ void k_batchout(float* __restrict__ out) {
    int i = blockIdx.x * blockDim.x + threadIdx.x;
    if (i >= 65536) return;
    int v = (i < 32768) ? (i >> 8) : ((i - 32768) >> 8) + 128;
    out[i] = (float)v;
}

// ---------------- launch ----------------
extern "C" void kernel_launch(void* const* d_in, const int* in_sizes, int n_in,
                              void* d_out, int out_size, void* d_ws, size_t ws_size,
                              hipStream_t stream) {
    const float* x    = (const float*)d_in[0];
    const int*   ei   = (const int*)d_in[1];
    const int*   esrc_in = ei;
    const int*   edst_in = ei + EDGES;
    const float* W1 = (const float*)d_in[2];  const float* b1 = (const float*)d_in[3];
    const float* W2 = (const float*)d_in[4];  const float* b2 = (const float*)d_in[5];
    const float* W3 = (const float*)d_in[6];  const float* b3 = (const float*)d_in[7];
    const float* pWr = (const float*)d_in[8]; const float* pWs = (const float*)d_in[9];
    const float* pb  = (const float*)d_in[10];
    const float* fW  = (const float*)d_in[11]; const float* fb = (const float*)d_in[12];
    const float* gpW = (const float*)d_in[13];
    const float* l1W = (const float*)d_in[14]; const float* l1b = (const float*)d_in[15];
    const float* l2W = (const float*)d_in[16]; const float* l2b = (const float*)d_in[17];
    const float* l3W = (const float*)d_in[18]; const float* l3b = (const float*)d_in[19];
    float* out = (float*)d_out;

    char* ws = (char*)d_ws;
    float* hcat  = (float*)(ws + OFF_HCAT);
    float* xw    = (float*)(ws + OFF_XW);
    float* xwp   = (float*)(ws + OFF_XW);                 // reuse after conv3
    float* hp    = (float*)(ws + OFF_XW + 16777216ull);
    float* dinv  = (float*)(ws + OFF_DINV);
    float* dinvp = (float*)(ws + OFF_DINVP);
    int*   offA  = (int*)(ws + OFF_OFFA);
    int*   cnt   = (int*)(ws + OFF_CNT);
    int*   esrc  = (int*)(ws + OFF_ESRC);
    float* xr    = (float*)(ws + OFF_XR);
    float* xs    = (float*)(ws + OFF_XS);
    float* score = (float*)(ws + OFF_SCORE);
    int*   pos   = (int*)(ws + OFF_POS);
    int*   keepn = (int*)(ws + OFF_KEEPN);
    float* keeps = (float*)(ws + OFF_KEEPS);
    int*   sums  = (int*)(ws + OFF_SUMS);
    float* xsum  = (float*)(ws + OFF_XSUM);
    float* cg    = (float*)(ws + OFF_CG);
    float* alpha = (float*)(ws + OFF_ALPHA);
    float* pvec  = (float*)(ws + OFF_PVEC);
    short* wt1   = (short*)(ws + OFF_WT1);
    short* wt2   = (short*)(ws + OFF_WT2);
    short* wt3   = (short*)(ws + OFF_WT3);
    short* wtf   = (short*)(ws + OFF_WTF);

    // ---- weight split prep (one launch) ----
    k_wsplit_all<<<384, 256, 0, stream>>>(W1, W2, W3, fW, wt1, wt2, wt3, wtf);

    // ---- full-graph CSR (by dst) ----
    hipMemsetAsync(cnt, 0, NNODE * sizeof(int), stream);
    k_hist<<<EDGES / 256, 256, 0, stream>>>(edst_in, cnt, EDGES);
    k_scan_a<<<NNODE / 256, 256, 0, stream>>>(cnt, offA, sums, NNODE);
    k_scan_b<<<1, 256, 0, stream>>>(sums, NNODE / 256, offA, NNODE);
    k_scan_c<<<NNODE / 256, 256, 0, stream>>>(offA, sums, NNODE);
    hipMemsetAsync(cnt, 0, NNODE * sizeof(int), stream);
    k_fill<<<EDGES / 256, 256, 0, stream>>>(esrc_in, edst_in, offA, cnt, esrc, EDGES);
    k_dinv<<<NNODE / 256, 256, 0, stream>>>(offA, dinv, NNODE);

    // ---- 3 GCN layers into hcat column slices ----
    k_gemm2<false><<<NNODE / 64, 256, 0, stream>>>(x, 128, 128, nullptr, nullptr, wt1, xw);
    k_agg4<512><<<BG * 8, 512, 0, stream>>>(xw, offA, esrc, dinv, b1, hcat + 0, DCAT);
    k_gemm2<false><<<NNODE / 64, 256, 0, stream>>>(hcat, DCAT, 128, nullptr, nullptr, wt2, xw);
    k_agg4<512><<<BG * 8, 512, 0, stream>>>(xw, offA, esrc, dinv, b2, hcat + 128, DCAT);
    k_gemm2<false><<<NNODE / 64, 256, 0, stream>>>(hcat + 128, DCAT, 128, nullptr, nullptr, wt3, xw);
    k_agg4<512><<<BG * 8, 512, 0, stream>>>(xw, offA, esrc, dinv, b3, hcat + 256, DCAT);

    // ---- SAGPool scoring + top-K ----
    k_xrxs<<<NNODE / 4, 256, 0, stream>>>(hcat, pWr, pWs, xr, xs);
    k_score<<<NNODE / 256, 256, 0, stream>>>(offA, esrc, xr, xs, pb, score);
    k_topk<<<256, 256, 0, stream>>>(score, keepn, keeps, pos);

    // ---- pooled CSR (filtered, remapped edges) ----
    hipMemsetAsync(cnt, 0, NPOOL * sizeof(int), stream);
    k_hist_p<<<EDGES / 256, 256, 0, stream>>>(esrc_in, edst_in, pos, cnt, EDGES);
    k_scan_a<<<NPOOL / 256, 256, 0, stream>>>(cnt, offA, sums, NPOOL);
    k_scan_b<<<1, 256, 0, stream>>>(sums, NPOOL / 256, offA, NPOOL);
    k_scan_c<<<NPOOL / 256, 256, 0, stream>>>(offA, sums, NPOOL);
    hipMemsetAsync(cnt, 0, NPOOL * sizeof(int), stream);
    k_fill_p<<<EDGES / 256, 256, 0, stream>>>(esrc_in, edst_in, pos, offA, cnt, esrc, EDGES);
    k_dinv<<<NPOOL / 256, 256, 0, stream>>>(offA, dinvp, NPOOL);

    // ---- pooled GCN conv (gather rows; score-scale applied in epilogue) ----
    k_gemm2<true><<<NPOOL / 64, 256, 0, stream>>>(hcat, DCAT, DCAT, keepn, keeps, wtf, xwp);
    k_agg4<128><<<NGG * 8, 512, 0, stream>>>(xwp, offA, esrc, dinvp, fb, hp, 128);

    // ---- attention pool + head ----
    k_xsum<<<NGG, 128, 0, stream>>>(hp, xsum);
    k_cg<<<NGG, 128, 0, stream>>>(xsum, gpW, cg);
    k_alpha<<<NPOOL / 4, 256, 0, stream>>>(hp, cg, alpha);
    k_wsum<<<NGG, 128, 0, stream>>>(hp, alpha, pvec);
    k_head<<<BG, 128, 0, stream>>>(pvec, l1W, l1b, l2W, l2b, l3W, l3b, out);
    k_batchout<<<256, 256, 0, stream>>>(out);
}

// Round 8
// 572.247 us; speedup vs baseline: 1.4089x; 1.1497x over previous
//
#include <hip/hip_runtime.h>
#include <hip/hip_bf16.h>

// ---------------- problem constants ----------------
#define BG     128        // graphs
#define NPG    512        // nodes per graph
#define NNODE  65536      // BG*NPG
#define EDGES  1048576    // BG*8192
#define NHID   128
#define DCAT   384
#define KKEEP  128        // kept nodes per (graph,cluster)
#define NPOOL  32768      // 2*BG*KKEEP
#define NGG    256        // pooled groups (2*BG)

// ---------------- workspace layout (bytes) ----------------
#define OFF_HCAT   0ull                       // 65536*384 f32 = 100663296
#define OFF_XW     100663296ull               // 65536*128 f32 (reused: xwp) ; hp at +16MB
#define OFF_DINV   134217728ull               // 65536 f32
#define OFF_DINVP  134479872ull               // 32768 f32
#define OFF_OFFA   134610944ull               // 65537 int
#define OFF_CNT    134873344ull               // 65536 int
#define OFF_ESRC   135135488ull               // 1048576 ushort (2MB, local ids)
#define OFF_XR     139329792ull               // 65536 f32
#define OFF_XS     139591936ull               // 65536 f32
#define OFF_SCORE  139854080ull               // 65536 f32
#define OFF_POS    140116224ull               // 65536 int
#define OFF_KEEPN  140378368ull               // 32768 int
#define OFF_KEEPS  140509440ull               // 32768 f32
#define OFF_SUMS   140640512ull               // 256 int
#define OFF_XSUM   140644608ull               // 256*128 f32
#define OFF_CG     140775680ull               // 256*128 f32
#define OFF_ALPHA  140906752ull               // 32768 f32
#define OFF_PVEC   141037824ull               // 256*128 f32 (ends 141168896)
#define OFF_WT1    141170688ull               // 2*128*128 short = 65536 (slot 98304)
#define OFF_WT2    141268992ull
#define OFF_WT3    141367296ull
#define OFF_WTF    141465600ull               // 2*128*384 short = 196608

typedef __attribute__((ext_vector_type(8))) short bf16x8;
typedef __attribute__((ext_vector_type(4))) float f32x4;

// bf16 round-to-nearest-even, result as high-aligned 32-bit pattern
__device__ inline unsigned rtn_hi(float x) {
    unsigned u = __builtin_bit_cast(unsigned, x);
    return (u + 0x7FFFu + ((u >> 16) & 1u)) & 0xFFFF0000u;
}

// split-2 RTN: x = h + m + eps, |eps| <~ 2^-18 |x|
__device__ inline void split2(const f32x4 v0, const f32x4 v1, bf16x8& ah, bf16x8& am) {
#pragma unroll
    for (int p = 0; p < 4; ++p) {
        float x0 = (p < 2) ? v0[2 * p] : v1[2 * p - 4];
        float x1 = (p < 2) ? v0[2 * p + 1] : v1[2 * p - 3];
        unsigned h0 = rtn_hi(x0), h1 = rtn_hi(x1);
        float r0 = x0 - __builtin_bit_cast(float, h0);
        float r1 = x1 - __builtin_bit_cast(float, h1);
        unsigned m0 = rtn_hi(r0), m1 = rtn_hi(r1);
        ah[2 * p] = (short)(h0 >> 16); ah[2 * p + 1] = (short)(h1 >> 16);
        am[2 * p] = (short)(m0 >> 16); am[2 * p + 1] = (short)(m1 >> 16);
    }
}

// ---------------- CSR build ----------------
__global__ void k_hist(const int* __restrict__ dst, int* __restrict__ cnt, int nE) {
    int e = blockIdx.x * blockDim.x + threadIdx.x;
    if (e < nE) atomicAdd(&cnt[dst[e]], 1);
}

__global__ void k_hist_p(const int* __restrict__ src, const int* __restrict__ dst,
                         const int* __restrict__ pos, int* __restrict__ cnt, int nE) {
    int e = blockIdx.x * blockDim.x + threadIdx.x;
    if (e >= nE) return;
    int s = src[e], d = dst[e];
    if ((((s ^ d) >> 8) & 1) != 0) return;    // must be same cluster side
    int ps = pos[s], pd = pos[d];
    if (ps >= 0 && pd >= 0) atomicAdd(&cnt[pd], 1);
}

__global__ void k_scan_a(const int* __restrict__ cnt, int* __restrict__ off,
                         int* __restrict__ sums, int n) {
    __shared__ int sh[256];
    int t = threadIdx.x;
    int i = blockIdx.x * 256 + t;
    int v = (i < n) ? cnt[i] : 0;
    sh[t] = v;
    __syncthreads();
    for (int d = 1; d < 256; d <<= 1) {
        int a = (t >= d) ? sh[t - d] : 0;
        __syncthreads();
        sh[t] += a;
        __syncthreads();
    }
    if (i < n) off[i] = sh[t] - v;            // local exclusive
    if (t == 255) sums[blockIdx.x] = sh[255]; // block total
}

__global__ void k_scan_b(int* __restrict__ sums, int nb, int* __restrict__ off, int n) {
    __shared__ int sh[256];
    int t = threadIdx.x;
    int v = (t < nb) ? sums[t] : 0;
    sh[t] = v;
    __syncthreads();
    for (int d = 1; d < 256; d <<= 1) {
        int a = (t >= d) ? sh[t - d] : 0;
        __syncthreads();
        sh[t] += a;
        __syncthreads();
    }
    if (t < nb) sums[t] = sh[t] - v;          // exclusive block offsets
    if (t == 255) off[n] = sh[255];           // grand total
}

__global__ void k_scan_c(int* __restrict__ off, const int* __restrict__ sums, int n) {
    int i = blockIdx.x * blockDim.x + threadIdx.x;
    if (i < n) off[i] += sums[i >> 8];
}

// store LOCAL src ids as u16 (NODESG<=512)
__global__ void k_fill(const int* __restrict__ src, const int* __restrict__ dst,
                       const int* __restrict__ off, int* __restrict__ cur,
                       unsigned short* __restrict__ es16, int nE) {
    int e = blockIdx.x * blockDim.x + threadIdx.x;
    if (e >= nE) return;
    int d = dst[e];
    int p = off[d] + atomicAdd(&cur[d], 1);
    es16[p] = (unsigned short)(src[e] & 511);
}

__global__ void k_fill_p(const int* __restrict__ src, const int* __restrict__ dst,
                         const int* __restrict__ pos, const int* __restrict__ off,
                         int* __restrict__ cur, unsigned short* __restrict__ es16, int nE) {
    int e = blockIdx.x * blockDim.x + threadIdx.x;
    if (e >= nE) return;
    int s = src[e], d = dst[e];
    if ((((s ^ d) >> 8) & 1) != 0) return;
    int ps = pos[s], pd = pos[d];
    if (ps < 0 || pd < 0) return;
    int p = off[pd] + atomicAdd(&cur[pd], 1);
    es16[p] = (unsigned short)(ps & 127);
}

__global__ void k_dinv(const int* __restrict__ off, float* __restrict__ dinv, int n) {
    int v = blockIdx.x * blockDim.x + threadIdx.x;
    if (v >= n) return;
    float deg = 1.0f + (float)(off[v + 1] - off[v]);
    dinv[v] = 1.0f / sqrtf(deg);
}

// ---------------- W split-2 prep: W[K][128] f32 -> 2 bf16 planes [128][K] ----
__device__ inline void wsplit_one(const float* W, short* Wt, int Kd, int i) {
    int tot = 128 * Kd;
    int n = i / Kd, k = i % Kd;
    float v = W[(size_t)k * 128 + n];
    unsigned h = rtn_hi(v);
    float r = v - __builtin_bit_cast(float, h);
    unsigned m = rtn_hi(r);
    Wt[i] = (short)(h >> 16);
    Wt[tot + i] = (short)(m >> 16);
}

__global__ void k_wsplit_all(const float* __restrict__ W1, const float* __restrict__ W2,
                             const float* __restrict__ W3, const float* __restrict__ Wf,
                             short* __restrict__ wt1, short* __restrict__ wt2,
                             short* __restrict__ wt3, short* __restrict__ wtf) {
    int i = blockIdx.x * 256 + threadIdx.x;
    if (i < 16384)      wsplit_one(W1, wt1, 128, i);
    else if (i < 32768) wsplit_one(W2, wt2, 128, i - 16384);
    else if (i < 49152) wsplit_one(W3, wt3, 128, i - 32768);
    else if (i < 98304) wsplit_one(Wf, wtf, 384, i - 49152);
}

// ---------------- MFMA split-2 GEMM, LDS-staged B: C[M][128] = A[M][Kd]@W[Kd][128] --
// 256 thr = 4 waves; block = 128 rows (2 tiles of 16 per wave, +64 apart).
// B staged per 64-K chunk in LDS (row stride 72 shorts: 16B aligned, 2-way max
// bank aliasing = free), shared by all waves & both tiles.
template <bool GATHER>
__global__ void __launch_bounds__(256)
k_gemmL(const float* __restrict__ A, int lda, int Kd,
        const int* __restrict__ rowmap, const float* __restrict__ rowscale,
        const short* __restrict__ Wt, float* __restrict__ C) {
    __shared__ short sB[256 * 72];          // [plane*128+n][72] (64 k + pad)
    int t = threadIdx.x;
    int w = t >> 6, l = t & 63;
    int m0 = blockIdx.x * 128;
    int mrow0 = m0 + (w << 4) + (l & 15);
    int mrow1 = mrow0 + 64;
    int arow0 = GATHER ? rowmap[mrow0] : mrow0;
    int arow1 = GATHER ? rowmap[mrow1] : mrow1;
    int kg = (l >> 4) << 3;                 // 0,8,16,24
    const float* ap0 = A + (size_t)arow0 * lda + kg;
    const float* ap1 = A + (size_t)arow1 * lda + kg;
    f32x4 acc0[8], acc1[8];
#pragma unroll
    for (int j = 0; j < 8; ++j) {
        acc0[j] = (f32x4){0.f, 0.f, 0.f, 0.f};
        acc1[j] = (f32x4){0.f, 0.f, 0.f, 0.f};
    }

    for (int kc = 0; kc < Kd; kc += 64) {
        if (kc) __syncthreads();
        // stage 2x128x64 shorts: flat 16B units, 8 units/row
#pragma unroll
        for (int i = 0; i < 8; ++i) {
            int u = t + i * 256;            // 0..2047
            int pr = u >> 3;                // plane*128+n
            int k8 = (u & 7) << 3;
            int plane = pr >> 7, n = pr & 127;
            bf16x8 vsrc = *reinterpret_cast<const bf16x8*>(
                &Wt[(size_t)(plane * 128 + n) * Kd + kc + k8]);
            *reinterpret_cast<bf16x8*>(&sB[pr * 72 + k8]) = vsrc;
        }
        __syncthreads();
#pragma unroll
        for (int ks = 0; ks < 2; ++ks) {
            int ko = ks * 32 + kg;
            f32x4 u0 = *reinterpret_cast<const f32x4*>(&ap0[kc + ks * 32]);
            f32x4 u1 = *reinterpret_cast<const f32x4*>(&ap0[kc + ks * 32 + 4]);
            f32x4 u2 = *reinterpret_cast<const f32x4*>(&ap1[kc + ks * 32]);
            f32x4 u3 = *reinterpret_cast<const f32x4*>(&ap1[kc + ks * 32 + 4]);
            bf16x8 aH0, aM0, aH1, aM1;
            split2(u0, u1, aH0, aM0);
            split2(u2, u3, aH1, aM1);
#pragma unroll
            for (int j = 0; j < 8; ++j) {
                int row = j * 16 + (l & 15);
                bf16x8 bH = *reinterpret_cast<const bf16x8*>(&sB[row * 72 + ko]);
                bf16x8 bM = *reinterpret_cast<const bf16x8*>(&sB[(128 + row) * 72 + ko]);
                acc0[j] = __builtin_amdgcn_mfma_f32_16x16x32_bf16(aH0, bH, acc0[j], 0, 0, 0);
                acc0[j] = __builtin_amdgcn_mfma_f32_16x16x32_bf16(aM0, bH, acc0[j], 0, 0, 0);
                acc0[j] = __builtin_amdgcn_mfma_f32_16x16x32_bf16(aH0, bM, acc0[j], 0, 0, 0);
                acc0[j] = __builtin_amdgcn_mfma_f32_16x16x32_bf16(aM0, bM, acc0[j], 0, 0, 0);
                acc1[j] = __builtin_amdgcn_mfma_f32_16x16x32_bf16(aH1, bH, acc1[j], 0, 0, 0);
                acc1[j] = __builtin_amdgcn_mfma_f32_16x16x32_bf16(aM1, bH, acc1[j], 0, 0, 0);
                acc1[j] = __builtin_amdgcn_mfma_f32_16x16x32_bf16(aH1, bM, acc1[j], 0, 0, 0);
                acc1[j] = __builtin_amdgcn_mfma_f32_16x16x32_bf16(aM1, bM, acc1[j], 0, 0, 0);
            }
        }
    }
    int cr0 = m0 + (w << 4) + ((l >> 4) << 2);
    int ccol = l & 15;
#pragma unroll
    for (int tile = 0; tile < 2; ++tile) {
        int cr = cr0 + tile * 64;
        f32x4* acc = tile ? acc1 : acc0;
        float rs0 = 1.f, rs1 = 1.f, rs2 = 1.f, rs3 = 1.f;
        if (GATHER) {
            rs0 = rowscale[cr]; rs1 = rowscale[cr + 1];
            rs2 = rowscale[cr + 2]; rs3 = rowscale[cr + 3];
        }
#pragma unroll
        for (int j = 0; j < 8; ++j) {
            C[(size_t)(cr + 0) * 128 + j * 16 + ccol] = acc[j][0] * rs0;
            C[(size_t)(cr + 1) * 128 + j * 16 + ccol] = acc[j][1] * rs1;
            C[(size_t)(cr + 2) * 128 + j * 16 + ccol] = acc[j][2] * rs2;
            C[(size_t)(cr + 3) * 128 + j * 16 + ccol] = acc[j][3] * rs3;
        }
    }
}

// ---------------- GCN aggregate: 16-ch blocks, 4 nodes/wave, prefetched edges ----
// u16 local src ids; next 16-edge chunk's load issued before processing current.
template <int NODESG>
__global__ void __launch_bounds__(512)
k_agg4(const float* __restrict__ xw, const int* __restrict__ off,
       const unsigned short* __restrict__ es16, const float* __restrict__ dinv,
       const float* __restrict__ bias, float* __restrict__ out, int ldout) {
    constexpr int STR = 17;
    __shared__ float sx[NODESG * STR];
    __shared__ float sdv[NODESG];
    int t = threadIdx.x;
    int lane = t & 63;
    int wv = t >> 6;                 // 0..7
    int sub = lane >> 4;             // 0..3
    int ch = lane & 15;
    int g  = blockIdx.x >> 3;        // group
    int hb = blockIdx.x & 7;         // channel block
    int ch0 = hb * 16;
    int gbase = g * NODESG;

    for (int r = t; r < NODESG; r += 512) sdv[r] = dinv[gbase + r];
    __syncthreads();
    for (int idx = t; idx < NODESG * 16; idx += 512) {
        int r = idx >> 4, c = idx & 15;
        sx[r * STR + c] = xw[(size_t)(gbase + r) * 128 + ch0 + c] * sdv[r];
    }
    __syncthreads();

    float bb = bias[ch0 + ch];
    for (int vi = wv * 4 + sub; vi < NODESG; vi += 32) {
        int v = gbase + vi;
        int e0 = off[v], e1 = off[v + 1];
        int deg = e1 - e0;
        float acc = sx[vi * STR + ch];       // self-loop (carries dinv[v])
        int cur = (ch < deg) ? (int)es16[e0 + ch] : 0;
        for (int base = 0; base < deg; base += 16) {
            int cnt = min(16, deg - base);
            int nidx = base + 16 + ch;
            int nxt = (nidx < deg) ? (int)es16[e0 + nidx] : 0;
            int k = 0;
            for (; k + 4 <= cnt; k += 4) {
                int s0 = __shfl(cur, k, 16);
                int s1 = __shfl(cur, k + 1, 16);
                int s2 = __shfl(cur, k + 2, 16);
                int s3 = __shfl(cur, k + 3, 16);
                float a0 = sx[s0 * STR + ch];
                float a1 = sx[s1 * STR + ch];
                float a2 = sx[s2 * STR + ch];
                float a3 = sx[s3 * STR + ch];
                acc += a0; acc += a1; acc += a2; acc += a3;
            }
            for (; k < cnt; ++k) {
                int s = __shfl(cur, k, 16);
                acc += sx[s * STR + ch];
            }
            cur = nxt;
        }
        out[(size_t)v * ldout + ch0 + ch] = fmaxf(fmaf(sdv[vi], acc, bb), 0.f);
    }
}

// ---------------- scoring ----------------
__global__ void k_xrxs(const float* __restrict__ hcat, const float* __restrict__ Wr,
                       const float* __restrict__ Ws, float* __restrict__ xr,
                       float* __restrict__ xs) {
    int wid  = (blockIdx.x * 256 + threadIdx.x) >> 6;   // node (wave per node)
    int lane = threadIdx.x & 63;
    if (wid >= NNODE) return;
    float ar = 0.f, as = 0.f;
#pragma unroll
    for (int k = lane; k < DCAT; k += 64) {
        float h = hcat[(size_t)wid * DCAT + k];
        ar = fmaf(h, Wr[k], ar);
        as = fmaf(h, Ws[k], as);
    }
    for (int o = 32; o; o >>= 1) { ar += __shfl_down(ar, o); as += __shfl_down(as, o); }
    if (lane == 0) { xr[wid] = ar; xs[wid] = as; }
}

__global__ void k_score(const int* __restrict__ off, const unsigned short* __restrict__ es16,
                        const float* __restrict__ xr, const float* __restrict__ xs,
                        const float* __restrict__ pb, float* __restrict__ score) {
    int v = blockIdx.x * blockDim.x + threadIdx.x;
    if (v >= NNODE) return;
    int side = (v >> 8) & 1;
    int gb = v & ~511;
    float acc = 0.f;
    int e0 = off[v], e1 = off[v + 1];
    for (int j = e0; j < e1; ++j) {
        int lsrc = (int)es16[j];
        if ((lsrc >> 8) == side) acc += xr[gb + lsrc];
    }
    score[v] = tanhf(acc + xs[v] + pb[0]);
}

// ---------------- per-(graph,cluster) top-K via bitonic sort ----------------
__global__ void k_topk(const float* __restrict__ score, int* __restrict__ keepn,
                       float* __restrict__ keeps, int* __restrict__ pos) {
    __shared__ unsigned long long keys[256];
    __shared__ float sc[256];
    __shared__ int rankof[256];
    int g = blockIdx.x & 127, cl = blockIdx.x >> 7;
    int t = threadIdx.x;
    int node = g * NPG + cl * 256 + t;
    float s = score[node];
    sc[t] = s;
    rankof[t] = -1;
    unsigned u = __float_as_uint(s);
    u = (u & 0x80000000u) ? ~u : (u | 0x80000000u); // ascending order map
    unsigned dk = ~u;                               // descending
    keys[t] = ((unsigned long long)dk << 32) | (unsigned)t;
    __syncthreads();
    for (int k = 2; k <= 256; k <<= 1)
        for (int j = k >> 1; j > 0; j >>= 1) {
            int ixj = t ^ j;
            if (ixj > t) {
                bool up = ((t & k) == 0);
                unsigned long long A = keys[t], Bk = keys[ixj];
                if ((A > Bk) == up) { keys[t] = Bk; keys[ixj] = A; }
            }
            __syncthreads();
        }
    if (t < KKEEP) {
        int idx = (int)(keys[t] & 0xffffffffu);
        int pool = cl * (BG * KKEEP) + g * KKEEP + t;
        keepn[pool] = g * NPG + cl * 256 + idx;
        keeps[pool] = sc[idx];
        rankof[idx] = t;
    }
    __syncthreads();
    int r = rankof[t];
    pos[node] = (r >= 0) ? (cl * (BG * KKEEP) + g * KKEEP + r) : -1;
}

// ---------------- attention pooling ----------------
__global__ void k_xsum(const float* __restrict__ hp, float* __restrict__ xsum) {
    int gg = blockIdx.x, t = threadIdx.x; // 256 blocks x 128 threads
    float a = 0.f;
#pragma unroll 8
    for (int i = 0; i < KKEEP; ++i) a += hp[(size_t)(gg * KKEEP + i) * 128 + t];
    xsum[gg * 128 + t] = a * (1.0f / (float)KKEEP);
}

__global__ void k_cg(const float* __restrict__ xsum, const float* __restrict__ gpW,
                     float* __restrict__ cg) {
    __shared__ float xl[128];
    int gg = blockIdx.x, t = threadIdx.x;
    xl[t] = xsum[gg * 128 + t];
    __syncthreads();
    float a = 0.f;
#pragma unroll 4
    for (int k = 0; k < 128; ++k) a = fmaf(xl[k], gpW[k * 128 + t], a);
    cg[gg * 128 + t] = tanhf(a);
}

__global__ void k_alpha(const float* __restrict__ hp, const float* __restrict__ cg,
                        float* __restrict__ alpha) {
    int node = (blockIdx.x * 256 + threadIdx.x) >> 6;
    int lane = threadIdx.x & 63;
    if (node >= NPOOL) return;
    int gg = node >> 7;
    float a = 0.f;
    for (int k = lane; k < 128; k += 64)
        a = fmaf(hp[(size_t)node * 128 + k], cg[gg * 128 + k], a);
    for (int o = 32; o; o >>= 1) a += __shfl_down(a, o);
    if (lane == 0) alpha[node] = 1.f / (1.f + expf(-a));
}

__global__ void k_wsum(const float* __restrict__ hp, const float* __restrict__ alpha,
                       float* __restrict__ pvec) {
    int gg = blockIdx.x, t = threadIdx.x;
    float a = 0.f;
#pragma unroll 8
    for (int i = 0; i < KKEEP; ++i) {
        int node = gg * KKEEP + i;
        a = fmaf(alpha[node], hp[(size_t)node * 128 + t], a);
    }
    pvec[gg * 128 + t] = a;
}

// ---------------- MLP head + outputs (f32 out) ----------------
__global__ void k_head(const float* __restrict__ pvec,
                       const float* __restrict__ l1W, const float* __restrict__ l1b,
                       const float* __restrict__ l2W, const float* __restrict__ l2b,
                       const float* __restrict__ l3W, const float* __restrict__ l3b,
                       float* __restrict__ out) {
    __shared__ float pv[256], h1[128], h2[64];
    int g = blockIdx.x, t = threadIdx.x;
    pv[t]       = pvec[g * 128 + t];
    pv[128 + t] = pvec[(128 + g) * 128 + t];
    __syncthreads();
    float a = l1b[t];
    for (int k = 0; k < 256; ++k) a = fmaf(pv[k], l1W[k * 128 + t], a);
    h1[t] = fmaxf(a, 0.f);
    __syncthreads();
    if (t < 64) {
        float a2 = l2b[t];
        for (int k = 0; k < 128; ++k) a2 = fmaf(h1[k], l2W[k * 64 + t], a2);
        h2[t] = fmaxf(a2, 0.f);
    }
    __syncthreads();
    if (t < 10) {
        float a3 = l3b[t];
        for (int k = 0; k < 64; ++k) a3 = fmaf(h2[k], l3W[k * 10 + t], a3);
        out[65536 + g * 10 + t] = a3;
    }
}

__global__ void k_batchout(float* __restrict__ out) {
    int i = blockIdx.x * blockDim.x + threadIdx.x;
    if (i >= 65536) return;
    int v = (i < 32768) ? (i >> 8) : ((i - 32768) >> 8) + 128;
    out[i] = (float)v;
}

// ---------------- launch ----------------
extern "C" void kernel_launch(void* const* d_in, const int* in_sizes, int n_in,
                              void* d_out, int out_size, void* d_ws, size_t ws_size,
                              hipStream_t stream) {
    const float* x    = (const float*)d_in[0];
    const int*   ei   = (const int*)d_in[1];
    const int*   esrc_in = ei;
    const int*   edst_in = ei + EDGES;
    const float* W1 = (const float*)d_in[2];  const float* b1 = (const float*)d_in[3];
    const float* W2 = (const float*)d_in[4];  const float* b2 = (const float*)d_in[5];
    const float* W3 = (const float*)d_in[6];  const float* b3 = (const float*)d_in[7];
    const float* pWr = (const float*)d_in[8]; const float* pWs = (const float*)d_in[9];
    const float* pb  = (const float*)d_in[10];
    const float* fW  = (const float*)d_in[11]; const float* fb = (const float*)d_in[12];
    const float* gpW = (const float*)d_in[13];
    const float* l1W = (const float*)d_in[14]; const float* l1b = (const float*)d_in[15];
    const float* l2W = (const float*)d_in[16]; const float* l2b = (const float*)d_in[17];
    const float* l3W = (const float*)d_in[18]; const float* l3b = (const float*)d_in[19];
    float* out = (float*)d_out;

    char* ws = (char*)d_ws;
    float* hcat  = (float*)(ws + OFF_HCAT);
    float* xw    = (float*)(ws + OFF_XW);
    float* xwp   = (float*)(ws + OFF_XW);                 // reuse after conv3
    float* hp    = (float*)(ws + OFF_XW + 16777216ull);
    float* dinv  = (float*)(ws + OFF_DINV);
    float* dinvp = (float*)(ws + OFF_DINVP);
    int*   offA  = (int*)(ws + OFF_OFFA);
    int*   cnt   = (int*)(ws + OFF_CNT);
    unsigned short* es16 = (unsigned short*)(ws + OFF_ESRC);
    float* xr    = (float*)(ws + OFF_XR);
    float* xs    = (float*)(ws + OFF_XS);
    float* score = (float*)(ws + OFF_SCORE);
    int*   pos   = (int*)(ws + OFF_POS);
    int*   keepn = (int*)(ws + OFF_KEEPN);
    float* keeps = (float*)(ws + OFF_KEEPS);
    int*   sums  = (int*)(ws + OFF_SUMS);
    float* xsum  = (float*)(ws + OFF_XSUM);
    float* cg    = (float*)(ws + OFF_CG);
    float* alpha = (float*)(ws + OFF_ALPHA);
    float* pvec  = (float*)(ws + OFF_PVEC);
    short* wt1   = (short*)(ws + OFF_WT1);
    short* wt2   = (short*)(ws + OFF_WT2);
    short* wt3   = (short*)(ws + OFF_WT3);
    short* wtf   = (short*)(ws + OFF_WTF);

    // ---- weight split prep (one launch) ----
    k_wsplit_all<<<384, 256, 0, stream>>>(W1, W2, W3, fW, wt1, wt2, wt3, wtf);

    // ---- full-graph CSR (by dst) ----
    hipMemsetAsync(cnt, 0, NNODE * sizeof(int), stream);
    k_hist<<<EDGES / 256, 256, 0, stream>>>(edst_in, cnt, EDGES);
    k_scan_a<<<NNODE / 256, 256, 0, stream>>>(cnt, offA, sums, NNODE);
    k_scan_b<<<1, 256, 0, stream>>>(sums, NNODE / 256, offA, NNODE);
    k_scan_c<<<NNODE / 256, 256, 0, stream>>>(offA, sums, NNODE);
    hipMemsetAsync(cnt, 0, NNODE * sizeof(int), stream);
    k_fill<<<EDGES / 256, 256, 0, stream>>>(esrc_in, edst_in, offA, cnt, es16, EDGES);
    k_dinv<<<NNODE / 256, 256, 0, stream>>>(offA, dinv, NNODE);

    // ---- 3 GCN layers into hcat column slices ----
    k_gemmL<false><<<NNODE / 128, 256, 0, stream>>>(x, 128, 128, nullptr, nullptr, wt1, xw);
    k_agg4<512><<<BG * 8, 512, 0, stream>>>(xw, offA, es16, dinv, b1, hcat + 0, DCAT);
    k_gemmL<false><<<NNODE / 128, 256, 0, stream>>>(hcat, DCAT, 128, nullptr, nullptr, wt2, xw);
    k_agg4<512><<<BG * 8, 512, 0, stream>>>(xw, offA, es16, dinv, b2, hcat + 128, DCAT);
    k_gemmL<false><<<NNODE / 128, 256, 0, stream>>>(hcat + 128, DCAT, 128, nullptr, nullptr, wt3, xw);
    k_agg4<512><<<BG * 8, 512, 0, stream>>>(xw, offA, es16, dinv, b3, hcat + 256, DCAT);

    // ---- SAGPool scoring + top-K ----
    k_xrxs<<<NNODE / 4, 256, 0, stream>>>(hcat, pWr, pWs, xr, xs);
    k_score<<<NNODE / 256, 256, 0, stream>>>(offA, es16, xr, xs, pb, score);
    k_topk<<<256, 256, 0, stream>>>(score, keepn, keeps, pos);

    // ---- pooled CSR (filtered, remapped edges) ----
    hipMemsetAsync(cnt, 0, NPOOL * sizeof(int), stream);
    k_hist_p<<<EDGES / 256, 256, 0, stream>>>(esrc_in, edst_in, pos, cnt, EDGES);
    k_scan_a<<<NPOOL / 256, 256, 0, stream>>>(cnt, offA, sums, NPOOL);
    k_scan_b<<<1, 256, 0, stream>>>(sums, NPOOL / 256, offA, NPOOL);
    k_scan_c<<<NPOOL / 256, 256, 0, stream>>>(offA, sums, NPOOL);
    hipMemsetAsync(cnt, 0, NPOOL * sizeof(int), stream);
    k_fill_p<<<EDGES / 256, 256, 0, stream>>>(esrc_in, edst_in, pos, offA, cnt, es16, EDGES);
    k_dinv<<<NPOOL / 256, 256, 0, stream>>>(offA, dinvp, NPOOL);

    // ---- pooled GCN conv (gather rows; score-scale applied in epilogue) ----
    k_gemmL<true><<<NPOOL / 128, 256, 0, stream>>>(hcat, DCAT, DCAT, keepn, keeps, wtf, xwp);
    k_agg4<128><<<NGG * 8, 512, 0, stream>>>(xwp, offA, es16, dinvp, fb, hp, 128);

    // ---- attention pool + head ----
    k_xsum<<<NGG, 128, 0, stream>>>(hp, xsum);
    k_cg<<<NGG, 128, 0, stream>>>(xsum, gpW, cg);
    k_alpha<<<NPOOL / 4, 256, 0, stream>>>(hp, cg, alpha);
    k_wsum<<<NGG, 128, 0, stream>>>(hp, alpha, pvec);
    k_head<<<BG, 128, 0, stream>>>(pvec, l1W, l1b, l2W, l2b, l3W, l3b, out);
    k_batchout<<<256, 256, 0, stream>>>(out);
}

// Round 9
// 503.817 us; speedup vs baseline: 1.6003x; 1.1358x over previous
//
#include <hip/hip_runtime.h>
#include <hip/hip_bf16.h>

// ---------------- problem constants ----------------
#define BG     128        // graphs
#define NPG    512        // nodes per graph
#define NNODE  65536      // BG*NPG
#define EDGES  1048576    // BG*8192
#define NHID   128
#define DCAT   384
#define KKEEP  128        // kept nodes per (graph,cluster)
#define NPOOL  32768      // 2*BG*KKEEP
#define NGG    256        // pooled groups (2*BG)

// ---------------- workspace layout (bytes) ----------------
#define OFF_HCAT   0ull                       // 65536*384 f32 = 100663296
#define OFF_XW     100663296ull               // 65536*128 f32 (reused: xwp) ; hp at +16MB
#define OFF_DINV   134217728ull               // 65536 f32
#define OFF_DINVP  134479872ull               // 32768 f32
#define OFF_OFFA   134610944ull               // 65537 int
#define OFF_CNT    134873344ull               // 65536 int
#define OFF_ESRC   135135488ull               // 1048576 ushort (2MB, local ids)
#define OFF_XR     139329792ull               // 65536 f32
#define OFF_XS     139591936ull               // 65536 f32
#define OFF_SCORE  139854080ull               // 65536 f32
#define OFF_POS    140116224ull               // 65536 int
#define OFF_KEEPN  140378368ull               // 32768 int
#define OFF_KEEPS  140509440ull               // 32768 f32
#define OFF_SUMS   140640512ull               // 256 int
#define OFF_XSUM   140644608ull               // 256*128 f32
#define OFF_CG     140775680ull               // 256*128 f32
#define OFF_ALPHA  140906752ull               // 32768 f32
#define OFF_PVEC   141037824ull               // 256*128 f32 (ends 141168896)
#define OFF_WT1    141170688ull               // 2*128*128 short = 65536 (slot 98304)
#define OFF_WT2    141268992ull
#define OFF_WT3    141367296ull
#define OFF_WTF    141465600ull               // 2*128*384 short = 196608

typedef __attribute__((ext_vector_type(8))) short bf16x8;
typedef __attribute__((ext_vector_type(4))) float f32x4;

// bf16 round-to-nearest-even, result as high-aligned 32-bit pattern
__device__ inline unsigned rtn_hi(float x) {
    unsigned u = __builtin_bit_cast(unsigned, x);
    return (u + 0x7FFFu + ((u >> 16) & 1u)) & 0xFFFF0000u;
}

// split-2 RTN: x = h + m + eps, |eps| <~ 2^-18 |x|
__device__ inline void split2(const f32x4 v0, const f32x4 v1, bf16x8& ah, bf16x8& am) {
#pragma unroll
    for (int p = 0; p < 4; ++p) {
        float x0 = (p < 2) ? v0[2 * p] : v1[2 * p - 4];
        float x1 = (p < 2) ? v0[2 * p + 1] : v1[2 * p - 3];
        unsigned h0 = rtn_hi(x0), h1 = rtn_hi(x1);
        float r0 = x0 - __builtin_bit_cast(float, h0);
        float r1 = x1 - __builtin_bit_cast(float, h1);
        unsigned m0 = rtn_hi(r0), m1 = rtn_hi(r1);
        ah[2 * p] = (short)(h0 >> 16); ah[2 * p + 1] = (short)(h1 >> 16);
        am[2 * p] = (short)(m0 >> 16); am[2 * p + 1] = (short)(m1 >> 16);
    }
}

// ---------------- CSR build ----------------
__global__ void k_hist(const int* __restrict__ dst, int* __restrict__ cnt, int nE) {
    int e = blockIdx.x * blockDim.x + threadIdx.x;
    if (e < nE) atomicAdd(&cnt[dst[e]], 1);
}

__global__ void k_hist_p(const int* __restrict__ src, const int* __restrict__ dst,
                         const int* __restrict__ pos, int* __restrict__ cnt, int nE) {
    int e = blockIdx.x * blockDim.x + threadIdx.x;
    if (e >= nE) return;
    int s = src[e], d = dst[e];
    if ((((s ^ d) >> 8) & 1) != 0) return;    // must be same cluster side
    int ps = pos[s], pd = pos[d];
    if (ps >= 0 && pd >= 0) atomicAdd(&cnt[pd], 1);
}

__global__ void k_scan_a(const int* __restrict__ cnt, int* __restrict__ off,
                         int* __restrict__ sums, int n) {
    __shared__ int sh[256];
    int t = threadIdx.x;
    int i = blockIdx.x * 256 + t;
    int v = (i < n) ? cnt[i] : 0;
    sh[t] = v;
    __syncthreads();
    for (int d = 1; d < 256; d <<= 1) {
        int a = (t >= d) ? sh[t - d] : 0;
        __syncthreads();
        sh[t] += a;
        __syncthreads();
    }
    if (i < n) off[i] = sh[t] - v;            // local exclusive
    if (t == 255) sums[blockIdx.x] = sh[255]; // block total
}

__global__ void k_scan_b(int* __restrict__ sums, int nb, int* __restrict__ off, int n) {
    __shared__ int sh[256];
    int t = threadIdx.x;
    int v = (t < nb) ? sums[t] : 0;
    sh[t] = v;
    __syncthreads();
    for (int d = 1; d < 256; d <<= 1) {
        int a = (t >= d) ? sh[t - d] : 0;
        __syncthreads();
        sh[t] += a;
        __syncthreads();
    }
    if (t < nb) sums[t] = sh[t] - v;          // exclusive block offsets
    if (t == 255) off[n] = sh[255];           // grand total
}

__global__ void k_scan_c(int* __restrict__ off, const int* __restrict__ sums, int n) {
    int i = blockIdx.x * blockDim.x + threadIdx.x;
    if (i < n) off[i] += sums[i >> 8];
}

// store LOCAL src ids as u16 (NODESG<=512)
__global__ void k_fill(const int* __restrict__ src, const int* __restrict__ dst,
                       const int* __restrict__ off, int* __restrict__ cur,
                       unsigned short* __restrict__ es16, int nE) {
    int e = blockIdx.x * blockDim.x + threadIdx.x;
    if (e >= nE) return;
    int d = dst[e];
    int p = off[d] + atomicAdd(&cur[d], 1);
    es16[p] = (unsigned short)(src[e] & 511);
}

__global__ void k_fill_p(const int* __restrict__ src, const int* __restrict__ dst,
                         const int* __restrict__ pos, const int* __restrict__ off,
                         int* __restrict__ cur, unsigned short* __restrict__ es16, int nE) {
    int e = blockIdx.x * blockDim.x + threadIdx.x;
    if (e >= nE) return;
    int s = src[e], d = dst[e];
    if ((((s ^ d) >> 8) & 1) != 0) return;
    int ps = pos[s], pd = pos[d];
    if (ps < 0 || pd < 0) return;
    int p = off[pd] + atomicAdd(&cur[pd], 1);
    es16[p] = (unsigned short)(ps & 127);
}

__global__ void k_dinv(const int* __restrict__ off, float* __restrict__ dinv, int n) {
    int v = blockIdx.x * blockDim.x + threadIdx.x;
    if (v >= n) return;
    float deg = 1.0f + (float)(off[v + 1] - off[v]);
    dinv[v] = 1.0f / sqrtf(deg);
}

// ---------------- W split-2 prep: W[K][128] f32 -> 2 bf16 planes [128][K] ----
__device__ inline void wsplit_one(const float* W, short* Wt, int Kd, int i) {
    int tot = 128 * Kd;
    int n = i / Kd, k = i % Kd;
    float v = W[(size_t)k * 128 + n];
    unsigned h = rtn_hi(v);
    float r = v - __builtin_bit_cast(float, h);
    unsigned m = rtn_hi(r);
    Wt[i] = (short)(h >> 16);
    Wt[tot + i] = (short)(m >> 16);
}

__global__ void k_wsplit_all(const float* __restrict__ W1, const float* __restrict__ W2,
                             const float* __restrict__ W3, const float* __restrict__ Wf,
                             short* __restrict__ wt1, short* __restrict__ wt2,
                             short* __restrict__ wt3, short* __restrict__ wtf) {
    int i = blockIdx.x * 256 + threadIdx.x;
    if (i < 16384)      wsplit_one(W1, wt1, 128, i);
    else if (i < 32768) wsplit_one(W2, wt2, 128, i - 16384);
    else if (i < 49152) wsplit_one(W3, wt3, 128, i - 32768);
    else if (i < 98304) wsplit_one(Wf, wtf, 384, i - 49152);
}

// ---------------- MFMA split-2 GEMM, LDS-staged B: C[M][128] = A[M][Kd]@W[Kd][128] --
// 256 thr = 4 waves; block = 128 rows (2 tiles of 16 per wave, +64 apart).
// B staged per 64-K chunk in LDS (row stride 72 shorts), shared by all waves.
template <bool GATHER>
__global__ void __launch_bounds__(256)
k_gemmL(const float* __restrict__ A, int lda, int Kd,
        const int* __restrict__ rowmap, const float* __restrict__ rowscale,
        const short* __restrict__ Wt, float* __restrict__ C) {
    __shared__ short sB[256 * 72];          // [plane*128+n][72] (64 k + pad)
    int t = threadIdx.x;
    int w = t >> 6, l = t & 63;
    int m0 = blockIdx.x * 128;
    int mrow0 = m0 + (w << 4) + (l & 15);
    int mrow1 = mrow0 + 64;
    int arow0 = GATHER ? rowmap[mrow0] : mrow0;
    int arow1 = GATHER ? rowmap[mrow1] : mrow1;
    int kg = (l >> 4) << 3;                 // 0,8,16,24
    const float* ap0 = A + (size_t)arow0 * lda + kg;
    const float* ap1 = A + (size_t)arow1 * lda + kg;
    f32x4 acc0[8], acc1[8];
#pragma unroll
    for (int j = 0; j < 8; ++j) {
        acc0[j] = (f32x4){0.f, 0.f, 0.f, 0.f};
        acc1[j] = (f32x4){0.f, 0.f, 0.f, 0.f};
    }

    for (int kc = 0; kc < Kd; kc += 64) {
        if (kc) __syncthreads();
        // stage 2x128x64 shorts: flat 16B units, 8 units/row
#pragma unroll
        for (int i = 0; i < 8; ++i) {
            int u = t + i * 256;            // 0..2047
            int pr = u >> 3;                // plane*128+n
            int k8 = (u & 7) << 3;
            int plane = pr >> 7, n = pr & 127;
            bf16x8 vsrc = *reinterpret_cast<const bf16x8*>(
                &Wt[(size_t)(plane * 128 + n) * Kd + kc + k8]);
            *reinterpret_cast<bf16x8*>(&sB[pr * 72 + k8]) = vsrc;
        }
        __syncthreads();
#pragma unroll
        for (int ks = 0; ks < 2; ++ks) {
            int ko = ks * 32 + kg;
            f32x4 u0 = *reinterpret_cast<const f32x4*>(&ap0[kc + ks * 32]);
            f32x4 u1 = *reinterpret_cast<const f32x4*>(&ap0[kc + ks * 32 + 4]);
            f32x4 u2 = *reinterpret_cast<const f32x4*>(&ap1[kc + ks * 32]);
            f32x4 u3 = *reinterpret_cast<const f32x4*>(&ap1[kc + ks * 32 + 4]);
            bf16x8 aH0, aM0, aH1, aM1;
            split2(u0, u1, aH0, aM0);
            split2(u2, u3, aH1, aM1);
#pragma unroll
            for (int j = 0; j < 8; ++j) {
                int row = j * 16 + (l & 15);
                bf16x8 bH = *reinterpret_cast<const bf16x8*>(&sB[row * 72 + ko]);
                bf16x8 bM = *reinterpret_cast<const bf16x8*>(&sB[(128 + row) * 72 + ko]);
                acc0[j] = __builtin_amdgcn_mfma_f32_16x16x32_bf16(aH0, bH, acc0[j], 0, 0, 0);
                acc0[j] = __builtin_amdgcn_mfma_f32_16x16x32_bf16(aM0, bH, acc0[j], 0, 0, 0);
                acc0[j] = __builtin_amdgcn_mfma_f32_16x16x32_bf16(aH0, bM, acc0[j], 0, 0, 0);
                acc0[j] = __builtin_amdgcn_mfma_f32_16x16x32_bf16(aM0, bM, acc0[j], 0, 0, 0);
                acc1[j] = __builtin_amdgcn_mfma_f32_16x16x32_bf16(aH1, bH, acc1[j], 0, 0, 0);
                acc1[j] = __builtin_amdgcn_mfma_f32_16x16x32_bf16(aM1, bH, acc1[j], 0, 0, 0);
                acc1[j] = __builtin_amdgcn_mfma_f32_16x16x32_bf16(aH1, bM, acc1[j], 0, 0, 0);
                acc1[j] = __builtin_amdgcn_mfma_f32_16x16x32_bf16(aM1, bM, acc1[j], 0, 0, 0);
            }
        }
    }
    int cr0 = m0 + (w << 4) + ((l >> 4) << 2);
    int ccol = l & 15;
#pragma unroll
    for (int tile = 0; tile < 2; ++tile) {
        int cr = cr0 + tile * 64;
        f32x4* acc = tile ? acc1 : acc0;
        float rs0 = 1.f, rs1 = 1.f, rs2 = 1.f, rs3 = 1.f;
        if (GATHER) {
            rs0 = rowscale[cr]; rs1 = rowscale[cr + 1];
            rs2 = rowscale[cr + 2]; rs3 = rowscale[cr + 3];
        }
#pragma unroll
        for (int j = 0; j < 8; ++j) {
            C[(size_t)(cr + 0) * 128 + j * 16 + ccol] = acc[j][0] * rs0;
            C[(size_t)(cr + 1) * 128 + j * 16 + ccol] = acc[j][1] * rs1;
            C[(size_t)(cr + 2) * 128 + j * 16 + ccol] = acc[j][2] * rs2;
            C[(size_t)(cr + 3) * 128 + j * 16 + ccol] = acc[j][3] * rs3;
        }
    }
}

// ---------------- GCN aggregate: 32-ch blocks (float2/lane), 4 nodes/wave ----
// Halves DS ops per edge vs 16-ch version: 4 channel-replicas, b64 LDS reads.
template <int NODESG>
__global__ void __launch_bounds__(512)
k_agg5(const float* __restrict__ xw, const int* __restrict__ off,
       const unsigned short* __restrict__ es16, const float* __restrict__ dinv,
       const float* __restrict__ bias, float* __restrict__ out, int ldout) {
    constexpr int STR = 34;                  // floats; 136B rows (8B aligned)
    __shared__ float sx[NODESG * STR];
    __shared__ float sdv[NODESG];
    int t = threadIdx.x;
    int lane = t & 63;
    int wv = t >> 6;                 // 0..7
    int sub = lane >> 4;             // 0..3
    int ch = lane & 15;              // covers channels 2ch, 2ch+1
    int g  = blockIdx.x >> 2;        // group
    int hb = blockIdx.x & 3;         // channel block (32 cols)
    int ch0 = hb * 32;
    int gbase = g * NODESG;

    for (int r = t; r < NODESG; r += 512) sdv[r] = dinv[gbase + r];
    __syncthreads();
    for (int idx = t; idx < NODESG * 16; idx += 512) {
        int r = idx >> 4, c2 = (idx & 15) << 1;
        float2 v = *reinterpret_cast<const float2*>(
            &xw[(size_t)(gbase + r) * 128 + ch0 + c2]);
        float dv = sdv[r];
        sx[r * STR + c2]     = v.x * dv;
        sx[r * STR + c2 + 1] = v.y * dv;
    }
    __syncthreads();

    float bbx = bias[ch0 + 2 * ch];
    float bby = bias[ch0 + 2 * ch + 1];
    for (int vi = wv * 4 + sub; vi < NODESG; vi += 32) {
        int v = gbase + vi;
        int e0 = off[v], e1 = off[v + 1];
        int deg = e1 - e0;
        float2 self = *reinterpret_cast<const float2*>(&sx[vi * STR + 2 * ch]);
        float ax = self.x, ay = self.y;      // self-loop (carries dinv[v])
        int cur = (ch < deg) ? (int)es16[e0 + ch] : 0;
        for (int base = 0; base < deg; base += 16) {
            int cnt = min(16, deg - base);
            int nidx = base + 16 + ch;
            int nxt = (nidx < deg) ? (int)es16[e0 + nidx] : 0;
            int k = 0;
            for (; k + 4 <= cnt; k += 4) {
                int s0 = __shfl(cur, k, 16);
                int s1 = __shfl(cur, k + 1, 16);
                int s2 = __shfl(cur, k + 2, 16);
                int s3 = __shfl(cur, k + 3, 16);
                float2 a0 = *reinterpret_cast<const float2*>(&sx[s0 * STR + 2 * ch]);
                float2 a1 = *reinterpret_cast<const float2*>(&sx[s1 * STR + 2 * ch]);
                float2 a2 = *reinterpret_cast<const float2*>(&sx[s2 * STR + 2 * ch]);
                float2 a3 = *reinterpret_cast<const float2*>(&sx[s3 * STR + 2 * ch]);
                ax += a0.x; ay += a0.y;
                ax += a1.x; ay += a1.y;
                ax += a2.x; ay += a2.y;
                ax += a3.x; ay += a3.y;
            }
            for (; k < cnt; ++k) {
                int s = __shfl(cur, k, 16);
                float2 a = *reinterpret_cast<const float2*>(&sx[s * STR + 2 * ch]);
                ax += a.x; ay += a.y;
            }
            cur = nxt;
        }
        float dv = sdv[vi];
        float2 o;
        o.x = fmaxf(fmaf(dv, ax, bbx), 0.f);
        o.y = fmaxf(fmaf(dv, ay, bby), 0.f);
        *reinterpret_cast<float2*>(&out[(size_t)v * ldout + ch0 + 2 * ch]) = o;
    }
}

// ---------------- scoring ----------------
__global__ void k_xrxs(const float* __restrict__ hcat, const float* __restrict__ Wr,
                       const float* __restrict__ Ws, float* __restrict__ xr,
                       float* __restrict__ xs) {
    int wid  = (blockIdx.x * 256 + threadIdx.x) >> 6;   // node (wave per node)
    int lane = threadIdx.x & 63;
    if (wid >= NNODE) return;
    float ar = 0.f, as = 0.f;
#pragma unroll
    for (int k = lane; k < DCAT; k += 64) {
        float h = hcat[(size_t)wid * DCAT + k];
        ar = fmaf(h, Wr[k], ar);
        as = fmaf(h, Ws[k], as);
    }
    for (int o = 32; o; o >>= 1) { ar += __shfl_down(ar, o); as += __shfl_down(as, o); }
    if (lane == 0) { xr[wid] = ar; xs[wid] = as; }
}

__global__ void k_score(const int* __restrict__ off, const unsigned short* __restrict__ es16,
                        const float* __restrict__ xr, const float* __restrict__ xs,
                        const float* __restrict__ pb, float* __restrict__ score) {
    int v = blockIdx.x * blockDim.x + threadIdx.x;
    if (v >= NNODE) return;
    int side = (v >> 8) & 1;
    int gb = v & ~511;
    float acc = 0.f;
    int e0 = off[v], e1 = off[v + 1];
    for (int j = e0; j < e1; ++j) {
        int lsrc = (int)es16[j];
        if ((lsrc >> 8) == side) acc += xr[gb + lsrc];
    }
    score[v] = tanhf(acc + xs[v] + pb[0]);
}

// ---------------- per-(graph,cluster) top-K via bitonic sort ----------------
__global__ void k_topk(const float* __restrict__ score, int* __restrict__ keepn,
                       float* __restrict__ keeps, int* __restrict__ pos) {
    __shared__ unsigned long long keys[256];
    __shared__ float sc[256];
    __shared__ int rankof[256];
    int g = blockIdx.x & 127, cl = blockIdx.x >> 7;
    int t = threadIdx.x;
    int node = g * NPG + cl * 256 + t;
    float s = score[node];
    sc[t] = s;
    rankof[t] = -1;
    unsigned u = __float_as_uint(s);
    u = (u & 0x80000000u) ? ~u : (u | 0x80000000u); // ascending order map
    unsigned dk = ~u;                               // descending
    keys[t] = ((unsigned long long)dk << 32) | (unsigned)t;
    __syncthreads();
    for (int k = 2; k <= 256; k <<= 1)
        for (int j = k >> 1; j > 0; j >>= 1) {
            int ixj = t ^ j;
            if (ixj > t) {
                bool up = ((t & k) == 0);
                unsigned long long A = keys[t], Bk = keys[ixj];
                if ((A > Bk) == up) { keys[t] = Bk; keys[ixj] = A; }
            }
            __syncthreads();
        }
    if (t < KKEEP) {
        int idx = (int)(keys[t] & 0xffffffffu);
        int pool = cl * (BG * KKEEP) + g * KKEEP + t;
        keepn[pool] = g * NPG + cl * 256 + idx;
        keeps[pool] = sc[idx];
        rankof[idx] = t;
    }
    __syncthreads();
    int r = rankof[t];
    pos[node] = (r >= 0) ? (cl * (BG * KKEEP) + g * KKEEP + r) : -1;
}

// ---------------- attention pooling ----------------
__global__ void k_xsum(const float* __restrict__ hp, float* __restrict__ xsum) {
    int gg = blockIdx.x, t = threadIdx.x; // 256 blocks x 128 threads
    float a = 0.f;
#pragma unroll 8
    for (int i = 0; i < KKEEP; ++i) a += hp[(size_t)(gg * KKEEP + i) * 128 + t];
    xsum[gg * 128 + t] = a * (1.0f / (float)KKEEP);
}

__global__ void k_cg(const float* __restrict__ xsum, const float* __restrict__ gpW,
                     float* __restrict__ cg) {
    __shared__ float xl[128];
    int gg = blockIdx.x, t = threadIdx.x;
    xl[t] = xsum[gg * 128 + t];
    __syncthreads();
    float a = 0.f;
#pragma unroll 4
    for (int k = 0; k < 128; ++k) a = fmaf(xl[k], gpW[k * 128 + t], a);
    cg[gg * 128 + t] = tanhf(a);
}

__global__ void k_alpha(const float* __restrict__ hp, const float* __restrict__ cg,
                        float* __restrict__ alpha) {
    int node = (blockIdx.x * 256 + threadIdx.x) >> 6;
    int lane = threadIdx.x & 63;
    if (node >= NPOOL) return;
    int gg = node >> 7;
    float a = 0.f;
    for (int k = lane; k < 128; k += 64)
        a = fmaf(hp[(size_t)node * 128 + k], cg[gg * 128 + k], a);
    for (int o = 32; o; o >>= 1) a += __shfl_down(a, o);
    if (lane == 0) alpha[node] = 1.f / (1.f + expf(-a));
}

__global__ void k_wsum(const float* __restrict__ hp, const float* __restrict__ alpha,
                       float* __restrict__ pvec) {
    int gg = blockIdx.x, t = threadIdx.x;
    float a = 0.f;
#pragma unroll 8
    for (int i = 0; i < KKEEP; ++i) {
        int node = gg * KKEEP + i;
        a = fmaf(alpha[node], hp[(size_t)node * 128 + t], a);
    }
    pvec[gg * 128 + t] = a;
}

// ---------------- MLP head + outputs (f32 out) ----------------
__global__ void k_head(const float* __restrict__ pvec,
                       const float* __restrict__ l1W, const float* __restrict__ l1b,
                       const float* __restrict__ l2W, const float* __restrict__ l2b,
                       const float* __restrict__ l3W, const float* __restrict__ l3b,
                       float* __restrict__ out) {
    __shared__ float pv[256], h1[128], h2[64];
    int g = blockIdx.x, t = threadIdx.x;
    pv[t]       = pvec[g * 128 + t];
    pv[128 + t] = pvec[(128 + g) * 128 + t];
    __syncthreads();
    float a = l1b[t];
    for (int k = 0; k < 256; ++k) a = fmaf(pv[k], l1W[k * 128 + t], a);
    h1[t] = fmaxf(a, 0.f);
    __syncthreads();
    if (t < 64) {
        float a2 = l2b[t];
        for (int k = 0; k < 128; ++k) a2 = fmaf(h1[k], l2W[k * 64 + t], a2);
        h2[t] = fmaxf(a2, 0.f);
    }
    __syncthreads();
    if (t < 10) {
        float a3 = l3b[t];
        for (int k = 0; k < 64; ++k) a3 = fmaf(h2[k], l3W[k * 10 + t], a3);
        out[65536 + g * 10 + t] = a3;
    }
}

__global__ void k_batchout(float* __restrict__ out) {
    int i = blockIdx.x * blockDim.x + threadIdx.x;
    if (i >= 65536) return;
    int v = (i < 32768) ? (i >> 8) : ((i - 32768) >> 8) + 128;
    out[i] = (float)v;
}

// ---------------- launch ----------------
extern "C" void kernel_launch(void* const* d_in, const int* in_sizes, int n_in,
                              void* d_out, int out_size, void* d_ws, size_t ws_size,
                              hipStream_t stream) {
    const float* x    = (const float*)d_in[0];
    const int*   ei   = (const int*)d_in[1];
    const int*   esrc_in = ei;
    const int*   edst_in = ei + EDGES;
    const float* W1 = (const float*)d_in[2];  const float* b1 = (const float*)d_in[3];
    const float* W2 = (const float*)d_in[4];  const float* b2 = (const float*)d_in[5];
    const float* W3 = (const float*)d_in[6];  const float* b3 = (const float*)d_in[7];
    const float* pWr = (const float*)d_in[8]; const float* pWs = (const float*)d_in[9];
    const float* pb  = (const float*)d_in[10];
    const float* fW  = (const float*)d_in[11]; const float* fb = (const float*)d_in[12];
    const float* gpW = (const float*)d_in[13];
    const float* l1W = (const float*)d_in[14]; const float* l1b = (const float*)d_in[15];
    const float* l2W = (const float*)d_in[16]; const float* l2b = (const float*)d_in[17];
    const float* l3W = (const float*)d_in[18]; const float* l3b = (const float*)d_in[19];
    float* out = (float*)d_out;

    char* ws = (char*)d_ws;
    float* hcat  = (float*)(ws + OFF_HCAT);
    float* xw    = (float*)(ws + OFF_XW);
    float* xwp   = (float*)(ws + OFF_XW);                 // reuse after conv3
    float* hp    = (float*)(ws + OFF_XW + 16777216ull);
    float* dinv  = (float*)(ws + OFF_DINV);
    float* dinvp = (float*)(ws + OFF_DINVP);
    int*   offA  = (int*)(ws + OFF_OFFA);
    int*   cnt   = (int*)(ws + OFF_CNT);
    unsigned short* es16 = (unsigned short*)(ws + OFF_ESRC);
    float* xr    = (float*)(ws + OFF_XR);
    float* xs    = (float*)(ws + OFF_XS);
    float* score = (float*)(ws + OFF_SCORE);
    int*   pos   = (int*)(ws + OFF_POS);
    int*   keepn = (int*)(ws + OFF_KEEPN);
    float* keeps = (float*)(ws + OFF_KEEPS);
    int*   sums  = (int*)(ws + OFF_SUMS);
    float* xsum  = (float*)(ws + OFF_XSUM);
    float* cg    = (float*)(ws + OFF_CG);
    float* alpha = (float*)(ws + OFF_ALPHA);
    float* pvec  = (float*)(ws + OFF_PVEC);
    short* wt1   = (short*)(ws + OFF_WT1);
    short* wt2   = (short*)(ws + OFF_WT2);
    short* wt3   = (short*)(ws + OFF_WT3);
    short* wtf   = (short*)(ws + OFF_WTF);

    // ---- weight split prep (one launch) ----
    k_wsplit_all<<<384, 256, 0, stream>>>(W1, W2, W3, fW, wt1, wt2, wt3, wtf);

    // ---- full-graph CSR (by dst) ----
    hipMemsetAsync(cnt, 0, NNODE * sizeof(int), stream);
    k_hist<<<EDGES / 256, 256, 0, stream>>>(edst_in, cnt, EDGES);
    k_scan_a<<<NNODE / 256, 256, 0, stream>>>(cnt, offA, sums, NNODE);
    k_scan_b<<<1, 256, 0, stream>>>(sums, NNODE / 256, offA, NNODE);
    k_scan_c<<<NNODE / 256, 256, 0, stream>>>(offA, sums, NNODE);
    hipMemsetAsync(cnt, 0, NNODE * sizeof(int), stream);
    k_fill<<<EDGES / 256, 256, 0, stream>>>(esrc_in, edst_in, offA, cnt, es16, EDGES);
    k_dinv<<<NNODE / 256, 256, 0, stream>>>(offA, dinv, NNODE);

    // ---- 3 GCN layers into hcat column slices ----
    k_gemmL<false><<<NNODE / 128, 256, 0, stream>>>(x, 128, 128, nullptr, nullptr, wt1, xw);
    k_agg5<512><<<BG * 4, 512, 0, stream>>>(xw, offA, es16, dinv, b1, hcat + 0, DCAT);
    k_gemmL<false><<<NNODE / 128, 256, 0, stream>>>(hcat, DCAT, 128, nullptr, nullptr, wt2, xw);
    k_agg5<512><<<BG * 4, 512, 0, stream>>>(xw, offA, es16, dinv, b2, hcat + 128, DCAT);
    k_gemmL<false><<<NNODE / 128, 256, 0, stream>>>(hcat + 128, DCAT, 128, nullptr, nullptr, wt3, xw);
    k_agg5<512><<<BG * 4, 512, 0, stream>>>(xw, offA, es16, dinv, b3, hcat + 256, DCAT);

    // ---- SAGPool scoring + top-K ----
    k_xrxs<<<NNODE / 4, 256, 0, stream>>>(hcat, pWr, pWs, xr, xs);
    k_score<<<NNODE / 256, 256, 0, stream>>>(offA, es16, xr, xs, pb, score);
    k_topk<<<256, 256, 0, stream>>>(score, keepn, keeps, pos);

    // ---- pooled CSR (filtered, remapped edges) ----
    hipMemsetAsync(cnt, 0, NPOOL * sizeof(int), stream);
    k_hist_p<<<EDGES / 256, 256, 0, stream>>>(esrc_in, edst_in, pos, cnt, EDGES);
    k_scan_a<<<NPOOL / 256, 256, 0, stream>>>(cnt, offA, sums, NPOOL);
    k_scan_b<<<1, 256, 0, stream>>>(sums, NPOOL / 256, offA, NPOOL);
    k_scan_c<<<NPOOL / 256, 256, 0, stream>>>(offA, sums, NPOOL);
    hipMemsetAsync(cnt, 0, NPOOL * sizeof(int), stream);
    k_fill_p<<<EDGES / 256, 256, 0, stream>>>(esrc_in, edst_in, pos, offA, cnt, es16, EDGES);
    k_dinv<<<NPOOL / 256, 256, 0, stream>>>(offA, dinvp, NPOOL);

    // ---- pooled GCN conv (gather rows; score-scale applied in epilogue) ----
    k_gemmL<true><<<NPOOL / 128, 256, 0, stream>>>(hcat, DCAT, DCAT, keepn, keeps, wtf, xwp);
    k_agg5<128><<<NGG * 4, 512, 0, stream>>>(xwp, offA, es16, dinvp, fb, hp, 128);

    // ---- attention pool + head ----
    k_xsum<<<NGG, 128, 0, stream>>>(hp, xsum);
    k_cg<<<NGG, 128, 0, stream>>>(xsum, gpW, cg);
    k_alpha<<<NPOOL / 4, 256, 0, stream>>>(hp, cg, alpha);
    k_wsum<<<NGG, 128, 0, stream>>>(hp, alpha, pvec);
    k_head<<<BG, 128, 0, stream>>>(pvec, l1W, l1b, l2W, l2b, l3W, l3b, out);
    k_batchout<<<256, 256, 0, stream>>>(out);
}